// Round 1
// baseline (3605.946 us; speedup 1.0000x reference)
//
#include <hip/hip_runtime.h>

#define NN 128
#define NMASK 127
#define BS 32
#define HID 64
#define SPAT 16384  /* 128*128 */

// ---------------- Jacobi (numeric expert) -------------------------------
// u_new = u + (h^2/4) * (f + lap(u));  lap(u) = (nsum - 4u) * N^2
// => u_new = u + f/65536 + (nsum - 4u)/4
__global__ __launch_bounds__(256) void jacobi_kernel(
    const float* __restrict__ u, const float* __restrict__ f,
    float* __restrict__ out) {
  int idx = blockIdx.x * 256 + threadIdx.x;  // 0 .. BS*SPAT
  int rem = idx & (SPAT - 1);
  int base = idx - rem;
  int y = rem >> 7, x = rem & NMASK;
  int yp = (y + 1) & NMASK, ym = (y - 1) & NMASK;
  int xp = (x + 1) & NMASK, xm = (x - 1) & NMASK;
  float uc = u[idx];
  float ns = u[base + (ym << 7) + x] + u[base + (yp << 7) + x]
           + u[base + (y << 7) + xm] + u[base + (y << 7) + xp];
  out[idx] = uc + f[idx] * (1.0f / 65536.0f) + (ns - 4.0f * uc) * 0.25f;
}

// ---------------- residual: res = f + lap(u) ----------------------------
__global__ __launch_bounds__(256) void res_kernel(
    const float* __restrict__ u, const float* __restrict__ f,
    float* __restrict__ res, int b0) {
  int idx = blockIdx.x * 256 + threadIdx.x;  // 0 .. BC*SPAT (local)
  int rem = idx & (SPAT - 1);
  int bl = idx >> 14;
  int g = ((b0 + bl) << 14) + rem;
  int gbase = (b0 + bl) << 14;
  int y = rem >> 7, x = rem & NMASK;
  int yp = (y + 1) & NMASK, ym = (y - 1) & NMASK;
  int xp = (x + 1) & NMASK, xm = (x - 1) & NMASK;
  float uc = u[g];
  float ns = u[gbase + (ym << 7) + x] + u[gbase + (yp << 7) + x]
           + u[gbase + (y << 7) + xm] + u[gbase + (y << 7) + xp];
  res[idx] = f[g] + (ns - 4.0f * uc) * 16384.0f;
}

// ---------------- conv1: 1 -> 64 channels, ReLU -------------------------
__global__ __launch_bounds__(256) void conv1_kernel(
    const float* __restrict__ res, const float* __restrict__ w1,
    const float* __restrict__ b1, float* __restrict__ h1) {
  int idx = blockIdx.x * 256 + threadIdx.x;  // 0 .. BC*SPAT
  int rem = idx & (SPAT - 1);
  int bl = idx >> 14;
  int y = rem >> 7, x = rem & NMASK;
  const float* rb = res + ((size_t)bl << 14);
  float r[9];
#pragma unroll
  for (int dy = 0; dy < 3; ++dy) {
    int gy = (y + dy - 1) & NMASK;
#pragma unroll
    for (int dx = 0; dx < 3; ++dx) {
      int gx = (x + dx - 1) & NMASK;
      r[dy * 3 + dx] = rb[(gy << 7) + gx];
    }
  }
  float* hb = h1 + (((size_t)bl * HID) << 14) + rem;
#pragma unroll
  for (int co = 0; co < HID; ++co) {
    float a = b1[co];
#pragma unroll
    for (int t = 0; t < 9; ++t) a += w1[co * 9 + t] * r[t];
    hb[(size_t)co << 14] = a > 0.0f ? a : 0.0f;
  }
}

// ---------------- conv2: 64 -> 64 channels, ReLU (the heavy one) --------
// Block = 16x16 spatial tile of one sample; LDS-staged input in 4-channel
// chunks; 64 fp32 accumulators per thread; weights are wave-uniform
// (scalar loads) feeding v_fmac_f32.
__global__ __launch_bounds__(256) void conv2_kernel(
    const float* __restrict__ h1, const float* __restrict__ w2,
    const float* __restrict__ b2, float* __restrict__ h2) {
  int blk = blockIdx.x;
  int bl = blk >> 6;          // local sample
  int tile = blk & 63;        // 8x8 tiles
  int ty0 = (tile >> 3) << 4;
  int tx0 = (tile & 7) << 4;
  int tid = threadIdx.x;
  int tx = tid & 15, ty = tid >> 4;
  __shared__ float lin[4][18][18];
  float acc[HID];
#pragma unroll
  for (int c = 0; c < HID; ++c) acc[c] = b2[c];
  const float* hb = h1 + (((size_t)bl * HID) << 14);

#pragma unroll 1
  for (int cc = 0; cc < HID; cc += 4) {
    for (int i = tid; i < 4 * 324; i += 256) {
      int ci = i / 324;
      int rr = i - ci * 324;
      int iy = rr / 18;
      int ix = rr - iy * 18;
      int gy = (ty0 + iy - 1) & NMASK;
      int gx = (tx0 + ix - 1) & NMASK;
      lin[ci][iy][ix] = hb[((size_t)(cc + ci) << 14) + (gy << 7) + gx];
    }
    __syncthreads();
#pragma unroll 1
    for (int ci = 0; ci < 4; ++ci) {
      float r[9];
#pragma unroll
      for (int dy = 0; dy < 3; ++dy)
#pragma unroll
        for (int dx = 0; dx < 3; ++dx)
          r[dy * 3 + dx] = lin[ci][ty + dy][tx + dx];
      const float* wp = w2 + (cc + ci) * 9;
#pragma unroll
      for (int co = 0; co < HID; ++co) {
        const float* w = wp + co * HID * 9;
        float a = acc[co];
        a += w[0] * r[0];
        a += w[1] * r[1];
        a += w[2] * r[2];
        a += w[3] * r[3];
        a += w[4] * r[4];
        a += w[5] * r[5];
        a += w[6] * r[6];
        a += w[7] * r[7];
        a += w[8] * r[8];
        acc[co] = a;
      }
    }
    __syncthreads();
  }
  size_t ob = (((size_t)bl * HID) << 14) + ((ty0 + ty) << 7) + tx0 + tx;
#pragma unroll
  for (int co = 0; co < HID; ++co) {
    float a = acc[co];
    h2[ob + ((size_t)co << 14)] = a > 0.0f ? a : 0.0f;
  }
}

// ---------------- conv3: 64 -> 1 channel + u update ---------------------
__global__ __launch_bounds__(256) void conv3_kernel(
    const float* __restrict__ h2, const float* __restrict__ w3,
    const float* __restrict__ b3, const float* __restrict__ uprev,
    float* __restrict__ uout, int b0) {
  int blk = blockIdx.x;
  int bl = blk >> 6;
  int tile = blk & 63;
  int ty0 = (tile >> 3) << 4;
  int tx0 = (tile & 7) << 4;
  int tid = threadIdx.x;
  int tx = tid & 15, ty = tid >> 4;
  __shared__ float lin[4][18][18];
  float acc = b3[0];
  const float* hb = h2 + (((size_t)bl * HID) << 14);

#pragma unroll 1
  for (int cc = 0; cc < HID; cc += 4) {
    for (int i = tid; i < 4 * 324; i += 256) {
      int ci = i / 324;
      int rr = i - ci * 324;
      int iy = rr / 18;
      int ix = rr - iy * 18;
      int gy = (ty0 + iy - 1) & NMASK;
      int gx = (tx0 + ix - 1) & NMASK;
      lin[ci][iy][ix] = hb[((size_t)(cc + ci) << 14) + (gy << 7) + gx];
    }
    __syncthreads();
#pragma unroll 1
    for (int ci = 0; ci < 4; ++ci) {
      const float* w = w3 + (cc + ci) * 9;
#pragma unroll
      for (int dy = 0; dy < 3; ++dy)
#pragma unroll
        for (int dx = 0; dx < 3; ++dx)
          acc += w[dy * 3 + dx] * lin[ci][ty + dy][tx + dx];
    }
    __syncthreads();
  }
  int y = ty0 + ty, x = tx0 + tx;
  int g = ((b0 + bl) << 14) + (y << 7) + x;
  uout[g] = uprev[g] + acc;
}

// ---------------- routing scores ----------------------------------------
__global__ void scores_kernel(float* __restrict__ s) {
  int i = blockIdx.x * 256 + threadIdx.x;  // 0 .. 511
  if (i < 8 * BS * 2) {
    int it = i >> 6;   // / (BS*2)
    int k = i & 1;
    bool ml = (it & 3) == 3;
    s[i] = ml ? (float)k : (float)(1 - k);
  }
}

extern "C" void kernel_launch(void* const* d_in, const int* in_sizes, int n_in,
                              void* d_out, int out_size, void* d_ws,
                              size_t ws_size, hipStream_t stream) {
  (void)in_sizes; (void)n_in; (void)out_size;
  const float* f  = (const float*)d_in[0];
  const float* u0 = (const float*)d_in[1];
  const float* w1 = (const float*)d_in[2];
  const float* b1 = (const float*)d_in[3];
  const float* w2 = (const float*)d_in[4];
  const float* b2 = (const float*)d_in[5];
  const float* w3 = (const float*)d_in[6];
  const float* b3 = (const float*)d_in[7];

  float* preds  = (float*)d_out;                       // [8][32][128][128]
  float* scores = preds + (size_t)8 * BS * SPAT;       // [8][32][2]

  // workspace: res [BC*SPAT], h1/h2 [BC*HID*SPAT]; chunk batch if ws small
  size_t per_sample = (size_t)(SPAT + 2 * HID * SPAT) * sizeof(float);
  int BC = BS;
  while (BC > 1 && (size_t)BC * per_sample > ws_size) BC >>= 1;
  float* res = (float*)d_ws;
  float* h1 = res + (size_t)BC * SPAT;
  float* h2 = h1 + ((size_t)BC * HID) * SPAT;

  for (int it = 0; it < 8; ++it) {
    const float* up = (it == 0) ? u0 : preds + (size_t)(it - 1) * BS * SPAT;
    float* un = preds + (size_t)it * BS * SPAT;
    if ((it & 3) != 3) {
      jacobi_kernel<<<BS * SPAT / 256, 256, 0, stream>>>(up, f, un);
    } else {
      for (int b0 = 0; b0 < BS; b0 += BC) {
        res_kernel<<<BC * SPAT / 256, 256, 0, stream>>>(up, f, res, b0);
        conv1_kernel<<<BC * SPAT / 256, 256, 0, stream>>>(res, w1, b1, h1);
        conv2_kernel<<<BC * 64, 256, 0, stream>>>(h1, w2, b2, h2);
        conv3_kernel<<<BC * 64, 256, 0, stream>>>(h2, w3, b3, up, un, b0);
      }
    }
  }
  scores_kernel<<<2, 256, 0, stream>>>(scores);
}

// Round 2
// 475.037 us; speedup vs baseline: 7.5909x; 7.5909x over previous
//
#include <hip/hip_runtime.h>
#include <hip/hip_bf16.h>

#define BS 32
#define HID 64
#define SPAT 16384
#define NMASK 127

using short8  = __attribute__((ext_vector_type(8))) short;
using short4v = __attribute__((ext_vector_type(4))) short;
using f32x16  = __attribute__((ext_vector_type(16))) float;

__device__ inline short f2bf(float f) {
  __hip_bfloat16 h = __float2bfloat16(f);
  return *reinterpret_cast<short*>(&h);
}
__device__ inline float bf2f(short s) {
  return __uint_as_float(((unsigned)(unsigned short)s) << 16);
}

// ---------------- Jacobi (numeric expert) -------------------------------
__global__ __launch_bounds__(256) void jacobi_kernel(
    const float* __restrict__ u, const float* __restrict__ f,
    float* __restrict__ out) {
  int idx = blockIdx.x * 256 + threadIdx.x;
  int rem = idx & (SPAT - 1);
  int base = idx - rem;
  int y = rem >> 7, x = rem & NMASK;
  int yp = (y + 1) & NMASK, ym = (y - 1) & NMASK;
  int xp = (x + 1) & NMASK, xm = (x - 1) & NMASK;
  float uc = u[idx];
  float ns = u[base + (ym << 7) + x] + u[base + (yp << 7) + x]
           + u[base + (y << 7) + xm] + u[base + (y << 7) + xp];
  out[idx] = uc + f[idx] * (1.0f / 65536.0f) + (ns - 4.0f * uc) * 0.25f;
}

// ---------------- weight repack: w2[co][ci][t] -> w2a[co][t*64+ci] bf16 --
__global__ __launch_bounds__(256) void prep_w2(const float* __restrict__ w2,
                                               short* __restrict__ w2a) {
  int idx = blockIdx.x * 256 + threadIdx.x;
  if (idx < 64 * 576) {
    int co = idx / 576, rem = idx % 576;
    int t = rem >> 6, ci = rem & 63;
    w2a[idx] = f2bf(w2[(co * 64 + ci) * 9 + t]);
  }
}

// ---------------- fused res + conv1 + conv2 (MFMA) ----------------------
// block = 16x16 tile of one sample; writes h2 (bf16, channel-last) to global
__global__ __launch_bounds__(256) void mlstep_a(
    const float* __restrict__ u, const float* __restrict__ f,
    const float* __restrict__ w1, const float* __restrict__ b1,
    const short* __restrict__ w2a, const float* __restrict__ b2,
    short* __restrict__ h2g, int b0) {
  __shared__ __align__(16) short h1s[18 * 18 * 64];  // reused as h2t[16*16*64]
  __shared__ float u_s[22 * 22];
  __shared__ float res_s[20 * 20];
  int tid = threadIdx.x;
  int bl = blockIdx.x >> 6;
  int tile = blockIdx.x & 63;
  int y0 = (tile >> 3) << 4, x0 = (tile & 7) << 4;
  int b = b0 + bl;
  const float* ub = u + ((size_t)b << 14);
  const float* fb = f + ((size_t)b << 14);

  // stage u 22x22 (halo 3)
  for (int i = tid; i < 484; i += 256) {
    int uy = i / 22, ux = i % 22;
    int gy = (y0 + uy - 3) & NMASK, gx = (x0 + ux - 3) & NMASK;
    u_s[i] = ub[(gy << 7) + gx];
  }
  __syncthreads();
  // res 20x20: res_s[ry][rx] = res(y0+ry-2, x0+rx-2)
  for (int i = tid; i < 400; i += 256) {
    int ry = i / 20, rx = i % 20;
    float uc = u_s[(ry + 1) * 22 + rx + 1];
    float ns = u_s[ry * 22 + rx + 1] + u_s[(ry + 2) * 22 + rx + 1]
             + u_s[(ry + 1) * 22 + rx] + u_s[(ry + 1) * 22 + rx + 2];
    int gy = (y0 + ry - 2) & NMASK, gx = (x0 + rx - 2) & NMASK;
    res_s[i] = fb[(gy << 7) + gx] + (ns - 4.0f * uc) * 16384.0f;
  }
  __syncthreads();
  // conv1 -> h1s[yy][xx][ci^sw] bf16, 18x18 region (h1 at image y0+yy-1)
  for (int i = tid; i < 324; i += 256) {
    int yy = i / 18, xx = i % 18;
    float r[9];
#pragma unroll
    for (int dy = 0; dy < 3; ++dy)
#pragma unroll
      for (int dx = 0; dx < 3; ++dx)
        r[dy * 3 + dx] = res_s[(yy + dy) * 20 + xx + dx];
    int sw = (xx & 7) << 3;
#pragma unroll
    for (int g = 0; g < 8; ++g) {
      short8 o;
#pragma unroll
      for (int q = 0; q < 8; ++q) {
        int ci = 8 * g + q;
        float a = b1[ci];
#pragma unroll
        for (int t = 0; t < 9; ++t) a += w1[ci * 9 + t] * r[t];
        o[q] = f2bf(a > 0.f ? a : 0.f);
      }
      *reinterpret_cast<short8*>(&h1s[i * 64 + ((8 * g) ^ sw)]) = o;
    }
  }
  __syncthreads();

  // conv2: implicit GEMM, D[co][px] = sum_k A[co][k]*B[k][px], k = t*64+ci
  int lane = tid & 63, wv = tid >> 6;
  int co0 = (wv >> 1) * 32;       // wave's output-channel block
  int nbase = (wv & 1) * 128;     // wave's pixel half
  int l31 = lane & 31, lh = lane >> 5;
  f32x16 acc[4];
#pragma unroll
  for (int nt = 0; nt < 4; ++nt)
#pragma unroll
    for (int r = 0; r < 16; ++r)
      acc[nt][r] = b2[co0 + (r & 3) + 8 * (r >> 2) + 4 * lh];
  const short* wrow = w2a + (co0 + l31) * 576 + 8 * lh;
#pragma unroll 1
  for (int kc = 0; kc < 36; ++kc) {
    int t = kc >> 2, ci0 = (kc & 3) * 16;
    short8 afrag = *reinterpret_cast<const short8*>(&wrow[t * 64 + ci0]);
    int dy = t / 3, dx = t % 3;
    int cib = ci0 + 8 * lh;
#pragma unroll
    for (int nt = 0; nt < 4; ++nt) {
      int px = nbase + nt * 32 + l31;
      int y = px >> 4, x = px & 15;
      int yy = y + dy, xx = x + dx;
      short8 bfrag = *reinterpret_cast<const short8*>(
          &h1s[(yy * 18 + xx) * 64 + (cib ^ ((xx & 7) << 3))]);
      acc[nt] = __builtin_amdgcn_mfma_f32_32x32x16_bf16(afrag, bfrag, acc[nt],
                                                        0, 0, 0);
    }
  }
  __syncthreads();
  // acc -> h2t (reuse h1s) with ReLU, bf16, swizzled channel-last
  short* h2t = h1s;
#pragma unroll
  for (int nt = 0; nt < 4; ++nt) {
    int px = nbase + nt * 32 + l31;
    int x = px & 15;
    int sw = (x & 7) << 3;
#pragma unroll
    for (int g = 0; g < 4; ++g) {
      int cb = co0 + 8 * g + 4 * lh;
      short4v o;
#pragma unroll
      for (int q = 0; q < 4; ++q) {
        float a = acc[nt][4 * g + q];
        o[q] = f2bf(a > 0.f ? a : 0.f);
      }
      *reinterpret_cast<short4v*>(&h2t[px * 64 + (cb ^ sw)]) = o;
    }
  }
  __syncthreads();
  // coalesced global writeout of h2 tile (chunk-local sample index)
  size_t obase = (((size_t)bl << 14) << 6);
#pragma unroll
  for (int k = 0; k < 8; ++k) {
    int q = tid + (k << 8);
    int c8 = (q & 7) << 3;
    int p = q >> 3;
    int y = p >> 4, x = p & 15;
    short8 v = *reinterpret_cast<const short8*>(
        &h2t[p * 64 + (c8 ^ ((x & 7) << 3))]);
    size_t gi = obase + ((size_t)(((y0 + y) << 7) + x0 + x) << 6) + c8;
    *reinterpret_cast<short8*>(&h2g[gi]) = v;
  }
}

// ---------------- conv3 + u update --------------------------------------
__global__ __launch_bounds__(256) void mlstep_b(
    const short* __restrict__ h2g, const float* __restrict__ w3,
    const float* __restrict__ b3, const float* __restrict__ uprev,
    float* __restrict__ uout, int b0) {
  __shared__ __align__(16) short h2t[18 * 18 * 64];
  int tid = threadIdx.x;
  int bl = blockIdx.x >> 6;
  int tile = blockIdx.x & 63;
  int y0 = (tile >> 3) << 4, x0 = (tile & 7) << 4;
  const short* hb = h2g + (((size_t)bl << 14) << 6);
  for (int q = tid; q < 2592; q += 256) {
    int pos = q >> 3, c8 = (q & 7) << 3;
    int yy = pos / 18, xx = pos % 18;
    int gy = (y0 + yy - 1) & NMASK, gx = (x0 + xx - 1) & NMASK;
    short8 v = *reinterpret_cast<const short8*>(
        &hb[(((size_t)(gy << 7) + gx) << 6) + c8]);
    *reinterpret_cast<short8*>(&h2t[pos * 64 + (c8 ^ ((xx & 7) << 3))]) = v;
  }
  __syncthreads();
  int y = tid >> 4, x = tid & 15;
  float acc = b3[0];
#pragma unroll
  for (int t = 0; t < 9; ++t) {
    int dy = t / 3, dx = t % 3;
    int yy = y + dy, xx = x + dx;
    int sw = (xx & 7) << 3;
    const short* row = &h2t[(yy * 18 + xx) * 64];
#pragma unroll
    for (int g = 0; g < 8; ++g) {
      short8 v = *reinterpret_cast<const short8*>(&row[(8 * g) ^ sw]);
#pragma unroll
      for (int j = 0; j < 8; ++j)
        acc += w3[(8 * g + j) * 9 + t] * bf2f(v[j]);
    }
  }
  int b = b0 + bl;
  size_t gi = ((size_t)b << 14) + (((y0 + y) << 7) + x0 + x);
  uout[gi] = uprev[gi] + acc;
}

// ---------------- routing scores ----------------------------------------
__global__ void scores_kernel(float* __restrict__ s) {
  int i = blockIdx.x * 256 + threadIdx.x;
  if (i < 8 * BS * 2) {
    int it = i >> 6;
    int k = i & 1;
    bool ml = (it & 3) == 3;
    s[i] = ml ? (float)k : (float)(1 - k);
  }
}

extern "C" void kernel_launch(void* const* d_in, const int* in_sizes, int n_in,
                              void* d_out, int out_size, void* d_ws,
                              size_t ws_size, hipStream_t stream) {
  (void)in_sizes; (void)n_in; (void)out_size;
  const float* f  = (const float*)d_in[0];
  const float* u0 = (const float*)d_in[1];
  const float* w1 = (const float*)d_in[2];
  const float* b1 = (const float*)d_in[3];
  const float* w2 = (const float*)d_in[4];
  const float* b2 = (const float*)d_in[5];
  const float* w3 = (const float*)d_in[6];
  const float* b3 = (const float*)d_in[7];

  float* preds  = (float*)d_out;                  // [8][32][128][128]
  float* scores = preds + (size_t)8 * BS * SPAT;  // [8][32][2]

  short* w2a = (short*)d_ws;                      // 64*576 bf16 = 73728 B
  short* h2g = w2a + 64 * 576;                    // [BC][128][128][64] bf16
  size_t avail = ws_size > (size_t)(64 * 576 * 2) ? ws_size - 64 * 576 * 2 : 0;
  int BC = 32;
  while (BC > 1 && (size_t)BC * ((size_t)SPAT * 64 * 2) > avail) BC >>= 1;

  prep_w2<<<144, 256, 0, stream>>>(w2, w2a);

  for (int it = 0; it < 8; ++it) {
    const float* up = (it == 0) ? u0 : preds + (size_t)(it - 1) * BS * SPAT;
    float* un = preds + (size_t)it * BS * SPAT;
    if ((it & 3) != 3) {
      jacobi_kernel<<<BS * SPAT / 256, 256, 0, stream>>>(up, f, un);
    } else {
      for (int b0 = 0; b0 < BS; b0 += BC) {
        mlstep_a<<<BC * 64, 256, 0, stream>>>(up, f, w1, b1, w2a, b2, h2g, b0);
        mlstep_b<<<BC * 64, 256, 0, stream>>>(h2g, w3, b3, up, un, b0);
      }
    }
  }
  scores_kernel<<<2, 256, 0, stream>>>(scores);
}

// Round 3
// 309.840 us; speedup vs baseline: 11.6381x; 1.5332x over previous
//
#include <hip/hip_runtime.h>
#include <hip/hip_bf16.h>

#define BS 32
#define HID 64
#define SPAT 16384
#define NMASK 127

using short8  = __attribute__((ext_vector_type(8))) short;
using short4v = __attribute__((ext_vector_type(4))) short;
using f32x16  = __attribute__((ext_vector_type(16))) float;
using f32x4   = __attribute__((ext_vector_type(4))) float;

__device__ inline short f2bf(float f) {
  __hip_bfloat16 h = __float2bfloat16(f);
  return *reinterpret_cast<short*>(&h);
}
__device__ inline float bf2f(short s) {
  return __uint_as_float(((unsigned)(unsigned short)s) << 16);
}

// ---------------- weight repack ----------------------------------------
// w2a[co][t*64+ci] bf16 (64x576); w1a[ch][16] bf16 (taps padded 9->16)
__global__ __launch_bounds__(256) void prep_kernel(
    const float* __restrict__ w2, const float* __restrict__ w1,
    short* __restrict__ w2a, short* __restrict__ w1a) {
  int idx = blockIdx.x * 256 + threadIdx.x;
  if (idx < 36864) {
    int co = idx / 576, rem = idx % 576;
    int t = rem >> 6, ci = rem & 63;
    w2a[idx] = f2bf(w2[(co * 64 + ci) * 9 + t]);
  } else if (idx < 36864 + 1024) {
    int j = idx - 36864;
    int ch = j >> 4, t = j & 15;
    w1a[j] = (t < 9) ? f2bf(w1[ch * 9 + t]) : (short)0;
  }
}

// ---------------- fused 3x Jacobi + residual ---------------------------
// one block = 16x16 tile; computes u1,u2,u3 (written to preds) and
// res4 = f + lap(u3) written to res_ws for the following ML step.
__global__ __launch_bounds__(256) void jac3_kernel(
    const float* __restrict__ uin, const float* __restrict__ f,
    float* __restrict__ u1o, float* __restrict__ u2o,
    float* __restrict__ u3o, float* __restrict__ res_ws) {
  __shared__ float As[576];   // 24x24
  __shared__ float Bs[484];   // 22x22
  __shared__ float Fs[484];   // 22x22, coords = (y0-3+i, x0-3+j)
  int tid = threadIdx.x;
  int bl = blockIdx.x >> 6, tile = blockIdx.x & 63;
  int y0 = (tile >> 3) << 4, x0 = (tile & 7) << 4;
  const float* ub = uin + ((size_t)bl << 14);
  const float* fb = f + ((size_t)bl << 14);
  for (int i = tid; i < 576; i += 256) {
    int uy = i / 24, ux = i % 24;
    As[i] = ub[(((y0 + uy - 4) & NMASK) << 7) + ((x0 + ux - 4) & NMASK)];
  }
  for (int i = tid; i < 484; i += 256) {
    int uy = i / 22, ux = i % 22;
    Fs[i] = fb[(((y0 + uy - 3) & NMASK) << 7) + ((x0 + ux - 3) & NMASK)];
  }
  __syncthreads();
  // u1 (22x22) into Bs
  for (int i = tid; i < 484; i += 256) {
    int yy = i / 22, xx = i % 22;
    float uc = As[(yy + 1) * 24 + xx + 1];
    float ns = As[yy * 24 + xx + 1] + As[(yy + 2) * 24 + xx + 1]
             + As[(yy + 1) * 24 + xx] + As[(yy + 1) * 24 + xx + 2];
    Bs[i] = uc + Fs[i] * (1.f / 65536.f) + (ns - 4.f * uc) * 0.25f;
  }
  __syncthreads();
  {
    int y = tid >> 4, x = tid & 15;
    u1o[((size_t)bl << 14) + ((y0 + y) << 7) + x0 + x] = Bs[(y + 3) * 22 + x + 3];
  }
  // u2 (20x20) into As
  for (int i = tid; i < 400; i += 256) {
    int yy = i / 20, xx = i % 20;
    float uc = Bs[(yy + 1) * 22 + xx + 1];
    float ns = Bs[yy * 22 + xx + 1] + Bs[(yy + 2) * 22 + xx + 1]
             + Bs[(yy + 1) * 22 + xx] + Bs[(yy + 1) * 22 + xx + 2];
    As[i] = uc + Fs[(yy + 1) * 22 + xx + 1] * (1.f / 65536.f)
          + (ns - 4.f * uc) * 0.25f;
  }
  __syncthreads();
  {
    int y = tid >> 4, x = tid & 15;
    u2o[((size_t)bl << 14) + ((y0 + y) << 7) + x0 + x] = As[(y + 2) * 20 + x + 2];
  }
  // u3 (18x18) into Bs
  for (int i = tid; i < 324; i += 256) {
    int yy = i / 18, xx = i % 18;
    float uc = As[(yy + 1) * 20 + xx + 1];
    float ns = As[yy * 20 + xx + 1] + As[(yy + 2) * 20 + xx + 1]
             + As[(yy + 1) * 20 + xx] + As[(yy + 1) * 20 + xx + 2];
    Bs[i] = uc + Fs[(yy + 2) * 22 + xx + 2] * (1.f / 65536.f)
          + (ns - 4.f * uc) * 0.25f;
  }
  __syncthreads();
  {
    int y = tid >> 4, x = tid & 15;
    size_t gi = ((size_t)bl << 14) + ((y0 + y) << 7) + x0 + x;
    float uc = Bs[(y + 1) * 18 + x + 1];
    u3o[gi] = uc;
    float ns = Bs[y * 18 + x + 1] + Bs[(y + 2) * 18 + x + 1]
             + Bs[(y + 1) * 18 + x] + Bs[(y + 1) * 18 + x + 2];
    res_ws[gi] = Fs[(y + 3) * 22 + x + 3] + (ns - 4.f * uc) * 16384.f;
  }
}

// ---------------- fused conv1(MFMA) + conv2(MFMA) ----------------------
// h1 LDS layout: cg-major [cg=ci/8][pos(18x18)][8ci] -> conflict-free
// ds_read_b128 with compile-time immediate offsets in the conv2 loop.
__global__ __launch_bounds__(256) void mlstep_a(
    const float* __restrict__ res_ws,
    const short* __restrict__ w1a, const float* __restrict__ b1v,
    const short* __restrict__ w2a, const float* __restrict__ b2v,
    short* __restrict__ h2g, int b0) {
  __shared__ __align__(16) short h1g[8 * 324 * 8];  // 41472 B; reused as h2t
  __shared__ __align__(16) short B1s[2 * 352 * 8];  // 11264 B
  __shared__ float res_s[20 * 20];
  int tid = threadIdx.x;
  int bl = blockIdx.x >> 6;
  int tile = blockIdx.x & 63;
  int y0 = (tile >> 3) << 4, x0 = (tile & 7) << 4;
  const float* rb = res_ws + ((size_t)(b0 + bl) << 14);

  // stage res 20x20 (halo 2)
  for (int i = tid; i < 400; i += 256) {
    int ry = i / 20, rx = i % 20;
    res_s[i] = rb[(((y0 + ry - 2) & NMASK) << 7) + ((x0 + rx - 2) & NMASK)];
  }
  __syncthreads();
  // build B1 [kg][pos][8] bf16: k = tap index (9 used, 7 zero-pad)
  for (int i = tid; i < 352; i += 256) {
    short8 lo = {}, hi = {};
    if (i < 324) {
      int yy = i / 18, xx = i % 18;
#pragma unroll
      for (int t = 0; t < 8; ++t)
        lo[t] = f2bf(res_s[(yy + t / 3) * 20 + xx + t % 3]);
      hi[0] = f2bf(res_s[(yy + 2) * 20 + xx + 2]);
    }
    *reinterpret_cast<short8*>(&B1s[i * 8]) = lo;
    *reinterpret_cast<short8*>(&B1s[(352 + i) * 8]) = hi;
  }
  __syncthreads();

  int lane = tid & 63, wv = tid >> 6;
  int l31 = lane & 31, lh = lane >> 5;

  // conv1 via MFMA: D[ch][pos], pos groups of 32, 2 co-blocks
  {
    short8 a1lo = *reinterpret_cast<const short8*>(&w1a[l31 * 16 + 8 * lh]);
    short8 a1hi = *reinterpret_cast<const short8*>(&w1a[(32 + l31) * 16 + 8 * lh]);
    for (int g = wv; g < 11; g += 4) {
      int pos = g * 32 + l31;
      short8 bf = *reinterpret_cast<const short8*>(
          (const char*)B1s + lh * 5632 + pos * 16);
      f32x16 acc0, acc1;
#pragma unroll
      for (int r = 0; r < 16; ++r) { acc0[r] = 0.f; acc1[r] = 0.f; }
      acc0 = __builtin_amdgcn_mfma_f32_32x32x16_bf16(a1lo, bf, acc0, 0, 0, 0);
      acc1 = __builtin_amdgcn_mfma_f32_32x32x16_bf16(a1hi, bf, acc1, 0, 0, 0);
      if (pos < 324) {
#pragma unroll
        for (int q = 0; q < 4; ++q) {
          f32x4 bv0 = *reinterpret_cast<const f32x4*>(&b1v[8 * q + 4 * lh]);
          f32x4 bv1 = *reinterpret_cast<const f32x4*>(&b1v[32 + 8 * q + 4 * lh]);
          short4v o0, o1;
#pragma unroll
          for (int j = 0; j < 4; ++j) {
            float v0 = acc0[4 * q + j] + bv0[j];
            float v1 = acc1[4 * q + j] + bv1[j];
            o0[j] = f2bf(v0 > 0.f ? v0 : 0.f);
            o1[j] = f2bf(v1 > 0.f ? v1 : 0.f);
          }
          *reinterpret_cast<short4v*>(
              (char*)h1g + (q * 324 + pos) * 16 + 8 * lh) = o0;
          *reinterpret_cast<short4v*>(
              (char*)h1g + ((4 + q) * 324 + pos) * 16 + 8 * lh) = o1;
        }
      }
    }
  }
  __syncthreads();

  // conv2: D[co][px] = sum_k w2a[co][k] * h1[k][px], k = t*64+ci
  int co0 = (wv >> 1) * 32;
  int nbase = (wv & 1) * 128;
  const char* hb[4];
#pragma unroll
  for (int nt = 0; nt < 4; ++nt) {
    int px = nbase + nt * 32 + l31;
    int pos0 = (px >> 4) * 18 + (px & 15);
    hb[nt] = (const char*)h1g + lh * 5184 + pos0 * 16;
  }
  const short* wrow = w2a + (co0 + l31) * 576 + 8 * lh;
  f32x16 acc[4];
#pragma unroll
  for (int nt = 0; nt < 4; ++nt)
#pragma unroll
    for (int r = 0; r < 16; ++r) acc[nt][r] = 0.f;
#pragma unroll
  for (int t = 0; t < 9; ++t) {
    short8 af[4];
#pragma unroll
    for (int c = 0; c < 4; ++c)
      af[c] = *reinterpret_cast<const short8*>(&wrow[t * 64 + c * 16]);
#pragma unroll
    for (int c = 0; c < 4; ++c) {
#pragma unroll
      for (int nt = 0; nt < 4; ++nt) {
        short8 bf = *reinterpret_cast<const short8*>(
            hb[nt] + (c * 10368 + ((t / 3) * 18 + (t % 3)) * 16));
        acc[nt] = __builtin_amdgcn_mfma_f32_32x32x16_bf16(af[c], bf, acc[nt],
                                                          0, 0, 0);
      }
    }
  }
  __syncthreads();  // all conv2 reads of h1g done -> reuse as h2t

  short* h2t = h1g;
#pragma unroll
  for (int nt = 0; nt < 4; ++nt) {
    int px = nbase + nt * 32 + l31;
    int sw = (px & 7) << 3;
#pragma unroll
    for (int q = 0; q < 4; ++q) {
      f32x4 bv = *reinterpret_cast<const f32x4*>(&b2v[co0 + 8 * q + 4 * lh]);
      short4v o;
#pragma unroll
      for (int j = 0; j < 4; ++j) {
        float v = acc[nt][4 * q + j] + bv[j];
        o[j] = f2bf(v > 0.f ? v : 0.f);
      }
      int ch0 = co0 + 8 * q + 4 * lh;
      *reinterpret_cast<short4v*>(&h2t[px * 64 + (ch0 ^ sw)]) = o;
    }
  }
  __syncthreads();
  // coalesced global writeout of h2 tile (channel-last, linear)
  size_t obase = (((size_t)bl << 14) << 6);
#pragma unroll
  for (int k = 0; k < 8; ++k) {
    int q = tid + (k << 8);
    int c8 = (q & 7) << 3;
    int p = q >> 3;
    int y = p >> 4, x = p & 15;
    short8 v = *reinterpret_cast<const short8*>(
        &h2t[p * 64 + (c8 ^ ((x & 7) << 3))]);
    size_t gi = obase + ((size_t)(((y0 + y) << 7) + x0 + x) << 6) + c8;
    *reinterpret_cast<short8*>(&h2g[gi]) = v;
  }
}

// ---------------- conv3 + u update --------------------------------------
__global__ __launch_bounds__(256) void mlstep_b(
    const short* __restrict__ h2g, const float* __restrict__ w3,
    const float* __restrict__ b3, const float* __restrict__ uprev,
    float* __restrict__ uout, int b0) {
  __shared__ __align__(16) short h2t[18 * 18 * 64];
  int tid = threadIdx.x;
  int bl = blockIdx.x >> 6;
  int tile = blockIdx.x & 63;
  int y0 = (tile >> 3) << 4, x0 = (tile & 7) << 4;
  const short* hb = h2g + (((size_t)bl << 14) << 6);
  for (int q = tid; q < 2592; q += 256) {
    int pos = q >> 3, c8 = (q & 7) << 3;
    int yy = pos / 18, xx = pos % 18;
    int gy = (y0 + yy - 1) & NMASK, gx = (x0 + xx - 1) & NMASK;
    short8 v = *reinterpret_cast<const short8*>(
        &hb[(((size_t)(gy << 7) + gx) << 6) + c8]);
    *reinterpret_cast<short8*>(&h2t[pos * 64 + (c8 ^ ((xx & 7) << 3))]) = v;
  }
  __syncthreads();
  int y = tid >> 4, x = tid & 15;
  float acc = b3[0];
#pragma unroll
  for (int t = 0; t < 9; ++t) {
    int dy = t / 3, dx = t % 3;
    int yy = y + dy, xx = x + dx;
    int sw = (xx & 7) << 3;
    const short* row = &h2t[(yy * 18 + xx) * 64];
#pragma unroll
    for (int g = 0; g < 8; ++g) {
      short8 v = *reinterpret_cast<const short8*>(&row[(8 * g) ^ sw]);
#pragma unroll
      for (int j = 0; j < 8; ++j)
        acc += w3[(8 * g + j) * 9 + t] * bf2f(v[j]);
    }
  }
  int b = b0 + bl;
  size_t gi = ((size_t)b << 14) + (((y0 + y) << 7) + x0 + x);
  uout[gi] = uprev[gi] + acc;
}

// ---------------- routing scores ----------------------------------------
__global__ void scores_kernel(float* __restrict__ s) {
  int i = blockIdx.x * 256 + threadIdx.x;
  if (i < 8 * BS * 2) {
    int it = i >> 6;
    int k = i & 1;
    bool ml = (it & 3) == 3;
    s[i] = ml ? (float)k : (float)(1 - k);
  }
}

extern "C" void kernel_launch(void* const* d_in, const int* in_sizes, int n_in,
                              void* d_out, int out_size, void* d_ws,
                              size_t ws_size, hipStream_t stream) {
  (void)in_sizes; (void)n_in; (void)out_size;
  const float* f  = (const float*)d_in[0];
  const float* u0 = (const float*)d_in[1];
  const float* w1 = (const float*)d_in[2];
  const float* b1 = (const float*)d_in[3];
  const float* w2 = (const float*)d_in[4];
  const float* b2 = (const float*)d_in[5];
  const float* w3 = (const float*)d_in[6];
  const float* b3 = (const float*)d_in[7];

  float* preds  = (float*)d_out;                  // [8][32][128][128]
  float* scores = preds + (size_t)8 * BS * SPAT;  // [8][32][2]

  short* w2a = (short*)d_ws;                       // 73728 B
  short* w1a = w2a + 64 * 576;                     // 2048 B
  float* res_ws = (float*)(w1a + 1024);            // 2 MB
  short* h2g = (short*)(res_ws + (size_t)BS * SPAT);
  size_t fixed = (size_t)(64 * 576 + 1024) * 2 + (size_t)BS * SPAT * 4;
  size_t avail = ws_size > fixed ? ws_size - fixed : 0;
  int BC = 32;
  while (BC > 1 && (size_t)BC * ((size_t)SPAT * 64 * 2) > avail) BC >>= 1;

  prep_kernel<<<149, 256, 0, stream>>>(w2, w1, w2a, w1a);

  for (int p = 0; p < 2; ++p) {
    int it = 4 * p;
    const float* up = (p == 0) ? u0 : preds + (size_t)3 * BS * SPAT;
    float* u1o = preds + (size_t)(it + 0) * BS * SPAT;
    float* u2o = preds + (size_t)(it + 1) * BS * SPAT;
    float* u3o = preds + (size_t)(it + 2) * BS * SPAT;
    float* umo = preds + (size_t)(it + 3) * BS * SPAT;
    jac3_kernel<<<BS * 64, 256, 0, stream>>>(up, f, u1o, u2o, u3o, res_ws);
    for (int b0 = 0; b0 < BS; b0 += BC) {
      mlstep_a<<<BC * 64, 256, 0, stream>>>(res_ws, w1a, b1, w2a, b2, h2g, b0);
      mlstep_b<<<BC * 64, 256, 0, stream>>>(h2g, w3, b3, u3o, umo, b0);
    }
  }
  scores_kernel<<<2, 256, 0, stream>>>(scores);
}

// Round 4
// 215.991 us; speedup vs baseline: 16.6949x; 1.4345x over previous
//
#include <hip/hip_runtime.h>
#include <hip/hip_bf16.h>

#define BS 32
#define HID 64
#define SPAT 16384
#define NMASK 127

using short8  = __attribute__((ext_vector_type(8))) short;
using short4v = __attribute__((ext_vector_type(4))) short;
using f32x16  = __attribute__((ext_vector_type(16))) float;
using f32x4   = __attribute__((ext_vector_type(4))) float;

__device__ inline short f2bf(float f) {
  __hip_bfloat16 h = __float2bfloat16(f);
  return *reinterpret_cast<short*>(&h);
}

// ---------------- weight repack ----------------------------------------
// w2a[co][t*64+ci] bf16 (64x576); w1a[ch][16] bf16; w3a[t][ci] bf16 32x64
__global__ __launch_bounds__(256) void prep_kernel(
    const float* __restrict__ w2, const float* __restrict__ w1,
    const float* __restrict__ w3, short* __restrict__ w2a,
    short* __restrict__ w1a, short* __restrict__ w3a) {
  int idx = blockIdx.x * 256 + threadIdx.x;
  if (idx < 36864) {
    int co = idx / 576, rem = idx % 576;
    int t = rem >> 6, ci = rem & 63;
    w2a[idx] = f2bf(w2[(co * 64 + ci) * 9 + t]);
  } else if (idx < 36864 + 1024) {
    int j = idx - 36864;
    int ch = j >> 4, t = j & 15;
    w1a[j] = (t < 9) ? f2bf(w1[ch * 9 + t]) : (short)0;
  } else if (idx < 36864 + 1024 + 2048) {
    int j = idx - 36864 - 1024;
    int t = j >> 6, ci = j & 63;
    w3a[j] = (t < 9) ? f2bf(w3[ci * 9 + t]) : (short)0;
  }
}

// ---------------- fused 3x Jacobi + residual ---------------------------
__global__ __launch_bounds__(256) void jac3_kernel(
    const float* __restrict__ uin, const float* __restrict__ f,
    float* __restrict__ u1o, float* __restrict__ u2o,
    float* __restrict__ u3o, float* __restrict__ res_ws) {
  __shared__ float As[576];   // 24x24
  __shared__ float Bs[484];   // 22x22
  __shared__ float Fs[484];   // 22x22, coords = (y0-3+i, x0-3+j)
  int tid = threadIdx.x;
  int bl = blockIdx.x >> 6, tile = blockIdx.x & 63;
  int y0 = (tile >> 3) << 4, x0 = (tile & 7) << 4;
  const float* ub = uin + ((size_t)bl << 14);
  const float* fb = f + ((size_t)bl << 14);
  for (int i = tid; i < 576; i += 256) {
    int uy = i / 24, ux = i % 24;
    As[i] = ub[(((y0 + uy - 4) & NMASK) << 7) + ((x0 + ux - 4) & NMASK)];
  }
  for (int i = tid; i < 484; i += 256) {
    int uy = i / 22, ux = i % 22;
    Fs[i] = fb[(((y0 + uy - 3) & NMASK) << 7) + ((x0 + ux - 3) & NMASK)];
  }
  __syncthreads();
  for (int i = tid; i < 484; i += 256) {
    int yy = i / 22, xx = i % 22;
    float uc = As[(yy + 1) * 24 + xx + 1];
    float ns = As[yy * 24 + xx + 1] + As[(yy + 2) * 24 + xx + 1]
             + As[(yy + 1) * 24 + xx] + As[(yy + 1) * 24 + xx + 2];
    Bs[i] = uc + Fs[i] * (1.f / 65536.f) + (ns - 4.f * uc) * 0.25f;
  }
  __syncthreads();
  {
    int y = tid >> 4, x = tid & 15;
    u1o[((size_t)bl << 14) + ((y0 + y) << 7) + x0 + x] = Bs[(y + 3) * 22 + x + 3];
  }
  for (int i = tid; i < 400; i += 256) {
    int yy = i / 20, xx = i % 20;
    float uc = Bs[(yy + 1) * 22 + xx + 1];
    float ns = Bs[yy * 22 + xx + 1] + Bs[(yy + 2) * 22 + xx + 1]
             + Bs[(yy + 1) * 22 + xx] + Bs[(yy + 1) * 22 + xx + 2];
    As[i] = uc + Fs[(yy + 1) * 22 + xx + 1] * (1.f / 65536.f)
          + (ns - 4.f * uc) * 0.25f;
  }
  __syncthreads();
  {
    int y = tid >> 4, x = tid & 15;
    u2o[((size_t)bl << 14) + ((y0 + y) << 7) + x0 + x] = As[(y + 2) * 20 + x + 2];
  }
  for (int i = tid; i < 324; i += 256) {
    int yy = i / 18, xx = i % 18;
    float uc = As[(yy + 1) * 20 + xx + 1];
    float ns = As[yy * 20 + xx + 1] + As[(yy + 2) * 20 + xx + 1]
             + As[(yy + 1) * 20 + xx] + As[(yy + 1) * 20 + xx + 2];
    Bs[i] = uc + Fs[(yy + 2) * 22 + xx + 2] * (1.f / 65536.f)
          + (ns - 4.f * uc) * 0.25f;
  }
  __syncthreads();
  {
    int y = tid >> 4, x = tid & 15;
    size_t gi = ((size_t)bl << 14) + ((y0 + y) << 7) + x0 + x;
    float uc = Bs[(y + 1) * 18 + x + 1];
    u3o[gi] = uc;
    float ns = Bs[y * 18 + x + 1] + Bs[(y + 2) * 18 + x + 1]
             + Bs[(y + 1) * 18 + x] + Bs[(y + 1) * 18 + x + 2];
    res_ws[gi] = Fs[(y + 3) * 22 + x + 3] + (ns - 4.f * uc) * 16384.f;
  }
}

// ---------------- fused conv1 + conv2 + depthwise-conv3 (all MFMA) -----
// h1 LDS: cg-major [cg][pos(18x18)][8ci]; h2 LDS: cg-major [cg][px(256)][8]
// D[t][px] = sum_ci w3a[t][ci] * h2[ci][px]  written to D_ws planes.
__global__ __launch_bounds__(256) void mlstep_a(
    const float* __restrict__ res_ws,
    const short* __restrict__ w1a, const float* __restrict__ b1v,
    const short* __restrict__ w2a, const float* __restrict__ b2v,
    const short* __restrict__ w3a, float* __restrict__ D_ws,
    int b0, int BC) {
  __shared__ __align__(16) short h1g[8 * 324 * 8];  // 41472 B; reused as h2t
  __shared__ __align__(16) short B1s[2 * 352 * 8];  // 11264 B
  __shared__ float res_s[20 * 20];
  int tid = threadIdx.x;
  int bl = blockIdx.x >> 6;
  int tile = blockIdx.x & 63;
  int y0 = (tile >> 3) << 4, x0 = (tile & 7) << 4;
  const float* rb = res_ws + ((size_t)(b0 + bl) << 14);

  for (int i = tid; i < 400; i += 256) {
    int ry = i / 20, rx = i % 20;
    res_s[i] = rb[(((y0 + ry - 2) & NMASK) << 7) + ((x0 + rx - 2) & NMASK)];
  }
  __syncthreads();
  for (int i = tid; i < 352; i += 256) {
    short8 lo = {}, hi = {};
    if (i < 324) {
      int yy = i / 18, xx = i % 18;
#pragma unroll
      for (int t = 0; t < 8; ++t)
        lo[t] = f2bf(res_s[(yy + t / 3) * 20 + xx + t % 3]);
      hi[0] = f2bf(res_s[(yy + 2) * 20 + xx + 2]);
    }
    *reinterpret_cast<short8*>(&B1s[i * 8]) = lo;
    *reinterpret_cast<short8*>(&B1s[(352 + i) * 8]) = hi;
  }
  __syncthreads();

  int lane = tid & 63, wv = tid >> 6;
  int l31 = lane & 31, lh = lane >> 5;

  // conv1 via MFMA
  {
    short8 a1lo = *reinterpret_cast<const short8*>(&w1a[l31 * 16 + 8 * lh]);
    short8 a1hi = *reinterpret_cast<const short8*>(&w1a[(32 + l31) * 16 + 8 * lh]);
    for (int g = wv; g < 11; g += 4) {
      int pos = g * 32 + l31;
      short8 bf = *reinterpret_cast<const short8*>(
          (const char*)B1s + lh * 5632 + pos * 16);
      f32x16 acc0, acc1;
#pragma unroll
      for (int r = 0; r < 16; ++r) { acc0[r] = 0.f; acc1[r] = 0.f; }
      acc0 = __builtin_amdgcn_mfma_f32_32x32x16_bf16(a1lo, bf, acc0, 0, 0, 0);
      acc1 = __builtin_amdgcn_mfma_f32_32x32x16_bf16(a1hi, bf, acc1, 0, 0, 0);
      if (pos < 324) {
#pragma unroll
        for (int q = 0; q < 4; ++q) {
          f32x4 bv0 = *reinterpret_cast<const f32x4*>(&b1v[8 * q + 4 * lh]);
          f32x4 bv1 = *reinterpret_cast<const f32x4*>(&b1v[32 + 8 * q + 4 * lh]);
          short4v o0, o1;
#pragma unroll
          for (int j = 0; j < 4; ++j) {
            float v0 = acc0[4 * q + j] + bv0[j];
            float v1 = acc1[4 * q + j] + bv1[j];
            o0[j] = f2bf(v0 > 0.f ? v0 : 0.f);
            o1[j] = f2bf(v1 > 0.f ? v1 : 0.f);
          }
          *reinterpret_cast<short4v*>(
              (char*)h1g + (q * 324 + pos) * 16 + 8 * lh) = o0;
          *reinterpret_cast<short4v*>(
              (char*)h1g + ((4 + q) * 324 + pos) * 16 + 8 * lh) = o1;
        }
      }
    }
  }
  __syncthreads();

  // conv2: wave wv owns px [wv*64, wv*64+64), all 64 output channels
  const char* hb[2];
#pragma unroll
  for (int nt = 0; nt < 2; ++nt) {
    int px = wv * 64 + nt * 32 + l31;
    int pos0 = (px >> 4) * 18 + (px & 15);
    hb[nt] = (const char*)h1g + lh * 5184 + pos0 * 16;
  }
  const short* wrow0 = w2a + l31 * 576 + 8 * lh;
  const short* wrow1 = w2a + (32 + l31) * 576 + 8 * lh;
  f32x16 acc[2][2];  // [cob][nt]
#pragma unroll
  for (int cb = 0; cb < 2; ++cb)
#pragma unroll
    for (int nt = 0; nt < 2; ++nt)
#pragma unroll
      for (int r = 0; r < 16; ++r) acc[cb][nt][r] = 0.f;
#pragma unroll
  for (int t = 0; t < 9; ++t) {
#pragma unroll
    for (int c = 0; c < 4; ++c) {
      short8 af0 = *reinterpret_cast<const short8*>(&wrow0[t * 64 + c * 16]);
      short8 af1 = *reinterpret_cast<const short8*>(&wrow1[t * 64 + c * 16]);
#pragma unroll
      for (int nt = 0; nt < 2; ++nt) {
        short8 bf = *reinterpret_cast<const short8*>(
            hb[nt] + (c * 10368 + ((t / 3) * 18 + (t % 3)) * 16));
        acc[0][nt] = __builtin_amdgcn_mfma_f32_32x32x16_bf16(af0, bf,
                                                             acc[0][nt], 0, 0, 0);
        acc[1][nt] = __builtin_amdgcn_mfma_f32_32x32x16_bf16(af1, bf,
                                                             acc[1][nt], 0, 0, 0);
      }
    }
  }
  __syncthreads();  // conv2 reads of h1g done -> reuse as h2t

  // h2 (ReLU+bias, bf16) -> LDS cg-major [cg][px][8]
  short* h2t = h1g;
#pragma unroll
  for (int cb = 0; cb < 2; ++cb)
#pragma unroll
    for (int nt = 0; nt < 2; ++nt) {
      int px = wv * 64 + nt * 32 + l31;
#pragma unroll
      for (int q = 0; q < 4; ++q) {
        int ch0 = cb * 32 + 8 * q + 4 * lh;
        f32x4 bv = *reinterpret_cast<const f32x4*>(&b2v[ch0]);
        short4v o;
#pragma unroll
        for (int j = 0; j < 4; ++j) {
          float v = acc[cb][nt][4 * q + j] + bv[j];
          o[j] = f2bf(v > 0.f ? v : 0.f);
        }
        int cg = cb * 4 + q;
        *reinterpret_cast<short4v*>(&h2t[(cg * 256 + px) * 8 + 4 * lh]) = o;
      }
    }
  __syncthreads();

  // depthwise conv3: D[t][px] = sum_ci w3a[t][ci] h2[ci][px]
  short8 af3[4];
#pragma unroll
  for (int c = 0; c < 4; ++c)
    af3[c] = *reinterpret_cast<const short8*>(&w3a[l31 * 64 + c * 16 + 8 * lh]);
#pragma unroll
  for (int nt = 0; nt < 2; ++nt) {
    int pxb = wv * 64 + nt * 32;
    f32x16 d;
#pragma unroll
    for (int r = 0; r < 16; ++r) d[r] = 0.f;
#pragma unroll
    for (int c = 0; c < 4; ++c) {
      short8 bf = *reinterpret_cast<const short8*>(
          (const char*)h2t + ((2 * c + lh) * 256 + pxb + l31) * 16);
      d = __builtin_amdgcn_mfma_f32_32x32x16_bf16(af3[c], bf, d, 0, 0, 0);
    }
    int px = pxb + l31;
    int gpx = ((y0 + (px >> 4)) << 7) + x0 + (px & 15);
    if (lh == 0) {
#pragma unroll
      for (int r = 0; r < 4; ++r)
        D_ws[((size_t)(r * BC + bl) << 14) + gpx] = d[r];
      D_ws[((size_t)(8 * BC + bl) << 14) + gpx] = d[4];
    } else {
#pragma unroll
      for (int r = 0; r < 4; ++r)
        D_ws[((size_t)((4 + r) * BC + bl) << 14) + gpx] = d[r];
    }
  }
}

// ---------------- conv3 shift-sum + u update (memory-bound) -------------
__global__ __launch_bounds__(256) void mlstep_b(
    const float* __restrict__ D_ws, const float* __restrict__ b3,
    const float* __restrict__ uprev, float* __restrict__ uout,
    int b0, int BC) {
  int idx = blockIdx.x * 256 + threadIdx.x;
  int bl = idx >> 14;
  int rem = idx & (SPAT - 1);
  int y = rem >> 7, x = rem & NMASK;
  float acc = b3[0];
#pragma unroll
  for (int t = 0; t < 9; ++t) {
    int yy = (y + t / 3 - 1) & NMASK;
    int xx = (x + t % 3 - 1) & NMASK;
    acc += D_ws[((size_t)(t * BC + bl) << 14) + (yy << 7) + xx];
  }
  size_t g = ((size_t)(b0 + bl) << 14) + rem;
  uout[g] = uprev[g] + acc;
}

// ---------------- routing scores ----------------------------------------
__global__ void scores_kernel(float* __restrict__ s) {
  int i = blockIdx.x * 256 + threadIdx.x;
  if (i < 8 * BS * 2) {
    int it = i >> 6;
    int k = i & 1;
    bool ml = (it & 3) == 3;
    s[i] = ml ? (float)k : (float)(1 - k);
  }
}

extern "C" void kernel_launch(void* const* d_in, const int* in_sizes, int n_in,
                              void* d_out, int out_size, void* d_ws,
                              size_t ws_size, hipStream_t stream) {
  (void)in_sizes; (void)n_in; (void)out_size;
  const float* f  = (const float*)d_in[0];
  const float* u0 = (const float*)d_in[1];
  const float* w1 = (const float*)d_in[2];
  const float* b1 = (const float*)d_in[3];
  const float* w2 = (const float*)d_in[4];
  const float* b2 = (const float*)d_in[5];
  const float* w3 = (const float*)d_in[6];
  const float* b3 = (const float*)d_in[7];

  float* preds  = (float*)d_out;                  // [8][32][128][128]
  float* scores = preds + (size_t)8 * BS * SPAT;  // [8][32][2]

  short* w2a = (short*)d_ws;                       // 73728 B
  short* w1a = w2a + 64 * 576;                     // 2048 B
  short* w3a = w1a + 1024;                         // 4096 B
  float* res_ws = (float*)(w3a + 2048);            // 2 MB
  float* D_ws = res_ws + (size_t)BS * SPAT;        // 9*BC*64KB
  size_t fixed = (size_t)(64 * 576 + 1024 + 2048) * 2 + (size_t)BS * SPAT * 4;
  size_t avail = ws_size > fixed ? ws_size - fixed : 0;
  int BC = 32;
  while (BC > 1 && (size_t)BC * ((size_t)9 * SPAT * 4) > avail) BC >>= 1;

  prep_kernel<<<156, 256, 0, stream>>>(w2, w1, w3, w2a, w1a, w3a);

  for (int p = 0; p < 2; ++p) {
    int it = 4 * p;
    const float* up = (p == 0) ? u0 : preds + (size_t)3 * BS * SPAT;
    float* u1o = preds + (size_t)(it + 0) * BS * SPAT;
    float* u2o = preds + (size_t)(it + 1) * BS * SPAT;
    float* u3o = preds + (size_t)(it + 2) * BS * SPAT;
    float* umo = preds + (size_t)(it + 3) * BS * SPAT;
    jac3_kernel<<<BS * 64, 256, 0, stream>>>(up, f, u1o, u2o, u3o, res_ws);
    for (int b0 = 0; b0 < BS; b0 += BC) {
      mlstep_a<<<BC * 64, 256, 0, stream>>>(res_ws, w1a, b1, w2a, b2, w3a,
                                            D_ws, b0, BC);
      mlstep_b<<<BC * SPAT / 256, 256, 0, stream>>>(D_ws, b3, u3o, umo, b0, BC);
    }
  }
  scores_kernel<<<2, 256, 0, stream>>>(scores);
}

// Round 5
// 155.911 us; speedup vs baseline: 23.1282x; 1.3853x over previous
//
#include <hip/hip_runtime.h>
#include <hip/hip_bf16.h>

#define BS 32
#define SPAT 16384
#define NMASK 127

using short8  = __attribute__((ext_vector_type(8))) short;
using short4v = __attribute__((ext_vector_type(4))) short;
using f32x16  = __attribute__((ext_vector_type(16))) float;
using f32x4   = __attribute__((ext_vector_type(4))) float;

__device__ inline short f2bf(float f) {
  __hip_bfloat16 h = __float2bfloat16(f);
  return *reinterpret_cast<short*>(&h);
}

// ---------------- weight repack ----------------------------------------
// w2b[cob][t][c][lh][l31][8]: lane-coalesced MFMA A-fragments (1KB/fragment)
// w1a[ch][16]; w3b[c][lh][l31=t][8] lane-coalesced
__global__ __launch_bounds__(256) void prep_kernel(
    const float* __restrict__ w2, const float* __restrict__ w1,
    const float* __restrict__ w3, short* __restrict__ w2b,
    short* __restrict__ w1a, short* __restrict__ w3b) {
  int idx = blockIdx.x * 256 + threadIdx.x;
  if (idx < 36864) {
    int cob = idx / 18432, r = idx % 18432;
    int t = r / 2048, r2 = r & 2047;
    int c = r2 >> 9, lh = (r2 >> 8) & 1, l31 = (r2 >> 3) & 31, j = r2 & 7;
    int co = cob * 32 + l31, ci = c * 16 + 8 * lh + j;
    w2b[idx] = f2bf(w2[(co * 64 + ci) * 9 + t]);
  } else if (idx < 37888) {
    int j = idx - 36864;
    int ch = j >> 4, t = j & 15;
    w1a[j] = (t < 9) ? f2bf(w1[ch * 9 + t]) : (short)0;
  } else if (idx < 39936) {
    int q = idx - 37888;
    int c = q >> 9, lh = (q >> 8) & 1, l31 = (q >> 3) & 31, j = q & 7;
    int t = l31, ci = c * 16 + 8 * lh + j;
    w3b[q] = (t < 9) ? f2bf(w3[ci * 9 + t]) : (short)0;
  }
}

// ---------------- fused 3x Jacobi + residual ---------------------------
__global__ __launch_bounds__(256) void jac3_kernel(
    const float* __restrict__ uin, const float* __restrict__ f,
    float* __restrict__ u1o, float* __restrict__ u2o,
    float* __restrict__ u3o, float* __restrict__ res_ws) {
  __shared__ float As[576];   // 24x24
  __shared__ float Bs[484];   // 22x22
  __shared__ float Fs[484];   // 22x22, coords = (y0-3+i, x0-3+j)
  int tid = threadIdx.x;
  int bl = blockIdx.x >> 6, tile = blockIdx.x & 63;
  int y0 = (tile >> 3) << 4, x0 = (tile & 7) << 4;
  const float* ub = uin + ((size_t)bl << 14);
  const float* fb = f + ((size_t)bl << 14);
  for (int i = tid; i < 576; i += 256) {
    int uy = i / 24, ux = i % 24;
    As[i] = ub[(((y0 + uy - 4) & NMASK) << 7) + ((x0 + ux - 4) & NMASK)];
  }
  for (int i = tid; i < 484; i += 256) {
    int uy = i / 22, ux = i % 22;
    Fs[i] = fb[(((y0 + uy - 3) & NMASK) << 7) + ((x0 + ux - 3) & NMASK)];
  }
  __syncthreads();
  for (int i = tid; i < 484; i += 256) {
    int yy = i / 22, xx = i % 22;
    float uc = As[(yy + 1) * 24 + xx + 1];
    float ns = As[yy * 24 + xx + 1] + As[(yy + 2) * 24 + xx + 1]
             + As[(yy + 1) * 24 + xx] + As[(yy + 1) * 24 + xx + 2];
    Bs[i] = uc + Fs[i] * (1.f / 65536.f) + (ns - 4.f * uc) * 0.25f;
  }
  __syncthreads();
  {
    int y = tid >> 4, x = tid & 15;
    u1o[((size_t)bl << 14) + ((y0 + y) << 7) + x0 + x] = Bs[(y + 3) * 22 + x + 3];
  }
  for (int i = tid; i < 400; i += 256) {
    int yy = i / 20, xx = i % 20;
    float uc = Bs[(yy + 1) * 22 + xx + 1];
    float ns = Bs[yy * 22 + xx + 1] + Bs[(yy + 2) * 22 + xx + 1]
             + Bs[(yy + 1) * 22 + xx] + Bs[(yy + 1) * 22 + xx + 2];
    As[i] = uc + Fs[(yy + 1) * 22 + xx + 1] * (1.f / 65536.f)
          + (ns - 4.f * uc) * 0.25f;
  }
  __syncthreads();
  {
    int y = tid >> 4, x = tid & 15;
    u2o[((size_t)bl << 14) + ((y0 + y) << 7) + x0 + x] = As[(y + 2) * 20 + x + 2];
  }
  for (int i = tid; i < 324; i += 256) {
    int yy = i / 18, xx = i % 18;
    float uc = As[(yy + 1) * 20 + xx + 1];
    float ns = As[yy * 20 + xx + 1] + As[(yy + 2) * 20 + xx + 1]
             + As[(yy + 1) * 20 + xx] + As[(yy + 1) * 20 + xx + 2];
    Bs[i] = uc + Fs[(yy + 2) * 22 + xx + 2] * (1.f / 65536.f)
          + (ns - 4.f * uc) * 0.25f;
  }
  __syncthreads();
  {
    int y = tid >> 4, x = tid & 15;
    size_t gi = ((size_t)bl << 14) + ((y0 + y) << 7) + x0 + x;
    float uc = Bs[(y + 1) * 18 + x + 1];
    u3o[gi] = uc;
    float ns = Bs[y * 18 + x + 1] + Bs[(y + 2) * 18 + x + 1]
             + Bs[(y + 1) * 18 + x] + Bs[(y + 1) * 18 + x + 2];
    res_ws[gi] = Fs[(y + 3) * 22 + x + 3] + (ns - 4.f * uc) * 16384.f;
  }
}

// ---------------- fused conv1 + conv2 + depthwise-conv3 (all MFMA) -----
// 512 threads (8 waves); wave wv owns px [wv*32, wv*32+32), all 64 co.
__global__ __launch_bounds__(512, 4) void mlstep_a(
    const float* __restrict__ res_ws,
    const short* __restrict__ w1a, const float* __restrict__ b1v,
    const short* __restrict__ w2b, const float* __restrict__ b2v,
    const short* __restrict__ w3b, float* __restrict__ D_ws,
    int b0, int BC) {
  __shared__ __align__(16) char lds[52736];
  short* h1g = (short*)lds;            // [8cg][324][8] bf16; reused as h2t [8][256][8]
  float* res_s = (float*)lds;          // 20x20 fp32 (aliases h1g; dead before conv1)
  short* B1s = (short*)(lds + 41472);  // [2][352][8]
  int tid = threadIdx.x;
  int bl = blockIdx.x >> 6;
  int tile = blockIdx.x & 63;
  int y0 = (tile >> 3) << 4, x0 = (tile & 7) << 4;
  const float* rb = res_ws + ((size_t)(b0 + bl) << 14);

  if (tid < 400) {
    int ry = tid / 20, rx = tid % 20;
    res_s[tid] = rb[(((y0 + ry - 2) & NMASK) << 7) + ((x0 + rx - 2) & NMASK)];
  }
  __syncthreads();
  if (tid < 352) {
    short8 lo = {}, hi = {};
    if (tid < 324) {
      int yy = tid / 18, xx = tid % 18;
#pragma unroll
      for (int t = 0; t < 8; ++t)
        lo[t] = f2bf(res_s[(yy + t / 3) * 20 + xx + t % 3]);
      hi[0] = f2bf(res_s[(yy + 2) * 20 + xx + 2]);
    }
    *reinterpret_cast<short8*>(&B1s[tid * 8]) = lo;
    *reinterpret_cast<short8*>(&B1s[(352 + tid) * 8]) = hi;
  }
  __syncthreads();

  int lane = tid & 63, wv = tid >> 6;
  int l31 = lane & 31, lh = lane >> 5;

  // conv1 via MFMA (11 pos-groups over 8 waves)
  {
    short8 a1lo = *reinterpret_cast<const short8*>(&w1a[l31 * 16 + 8 * lh]);
    short8 a1hi = *reinterpret_cast<const short8*>(&w1a[(32 + l31) * 16 + 8 * lh]);
    for (int g = wv; g < 11; g += 8) {
      int pos = g * 32 + l31;
      short8 bf = *reinterpret_cast<const short8*>(
          (const char*)B1s + lh * 5632 + pos * 16);
      f32x16 acc0, acc1;
#pragma unroll
      for (int r = 0; r < 16; ++r) { acc0[r] = 0.f; acc1[r] = 0.f; }
      acc0 = __builtin_amdgcn_mfma_f32_32x32x16_bf16(a1lo, bf, acc0, 0, 0, 0);
      acc1 = __builtin_amdgcn_mfma_f32_32x32x16_bf16(a1hi, bf, acc1, 0, 0, 0);
      if (pos < 324) {
#pragma unroll
        for (int q = 0; q < 4; ++q) {
          f32x4 bv0 = *reinterpret_cast<const f32x4*>(&b1v[8 * q + 4 * lh]);
          f32x4 bv1 = *reinterpret_cast<const f32x4*>(&b1v[32 + 8 * q + 4 * lh]);
          short4v o0, o1;
#pragma unroll
          for (int j = 0; j < 4; ++j) {
            float v0 = acc0[4 * q + j] + bv0[j];
            float v1 = acc1[4 * q + j] + bv1[j];
            o0[j] = f2bf(v0 > 0.f ? v0 : 0.f);
            o1[j] = f2bf(v1 > 0.f ? v1 : 0.f);
          }
          *reinterpret_cast<short4v*>(
              (char*)h1g + (q * 324 + pos) * 16 + 8 * lh) = o0;
          *reinterpret_cast<short4v*>(
              (char*)h1g + ((4 + q) * 324 + pos) * 16 + 8 * lh) = o1;
        }
      }
    }
  }
  __syncthreads();

  // conv2: coalesced 1KB A-fragment loads, conflict-light LDS B-reads
  int px = (wv << 5) + l31;
  {
    int pos0 = (px >> 4) * 18 + (px & 15);
    const char* hb = (const char*)h1g + lh * 5184 + pos0 * 16;
    const char* wb = (const char*)w2b + lane * 16;
    f32x16 acc0, acc1;
#pragma unroll
    for (int r = 0; r < 16; ++r) { acc0[r] = 0.f; acc1[r] = 0.f; }
#pragma unroll
    for (int t = 0; t < 9; ++t) {
#pragma unroll
      for (int c = 0; c < 4; ++c) {
        short8 af0 = *reinterpret_cast<const short8*>(wb + (t * 4 + c) * 1024);
        short8 af1 = *reinterpret_cast<const short8*>(
            wb + ((9 + t) * 4 + c) * 1024);
        short8 bf = *reinterpret_cast<const short8*>(
            hb + c * 10368 + ((t / 3) * 18 + (t % 3)) * 16);
        acc0 = __builtin_amdgcn_mfma_f32_32x32x16_bf16(af0, bf, acc0, 0, 0, 0);
        acc1 = __builtin_amdgcn_mfma_f32_32x32x16_bf16(af1, bf, acc1, 0, 0, 0);
      }
    }
    __syncthreads();  // conv2 reads of h1g done -> reuse as h2t

    // h2 (ReLU+bias, bf16) -> LDS cg-major [cg][px][8]
    short* h2t = h1g;
#pragma unroll
    for (int cb = 0; cb < 2; ++cb) {
      const f32x16& a = cb ? acc1 : acc0;
#pragma unroll
      for (int q = 0; q < 4; ++q) {
        int ch0 = cb * 32 + 8 * q + 4 * lh;
        f32x4 bv = *reinterpret_cast<const f32x4*>(&b2v[ch0]);
        short4v o;
#pragma unroll
        for (int j = 0; j < 4; ++j) {
          float v = a[4 * q + j] + bv[j];
          o[j] = f2bf(v > 0.f ? v : 0.f);
        }
        int cg = cb * 4 + q;
        *reinterpret_cast<short4v*>(&h2t[(cg * 256 + px) * 8 + 4 * lh]) = o;
      }
    }
    // depthwise conv3 — wave-local px, no barrier needed
    f32x16 d;
#pragma unroll
    for (int r = 0; r < 16; ++r) d[r] = 0.f;
#pragma unroll
    for (int c = 0; c < 4; ++c) {
      short8 af3 = *reinterpret_cast<const short8*>(
          (const char*)w3b + c * 1024 + lane * 16);
      short8 bf = *reinterpret_cast<const short8*>(
          (const char*)h2t + ((2 * c + lh) * 256 + px) * 16);
      d = __builtin_amdgcn_mfma_f32_32x32x16_bf16(af3, bf, d, 0, 0, 0);
    }
    int gpx = ((y0 + (px >> 4)) << 7) + x0 + (px & 15);
    if (lh == 0) {
#pragma unroll
      for (int r = 0; r < 4; ++r)
        D_ws[((size_t)(r * BC + bl) << 14) + gpx] = d[r];
      D_ws[((size_t)(8 * BC + bl) << 14) + gpx] = d[4];
    } else {
#pragma unroll
      for (int r = 0; r < 4; ++r)
        D_ws[((size_t)((4 + r) * BC + bl) << 14) + gpx] = d[r];
    }
  }
}

// ---------------- conv3 shift-sum + u update (memory-bound) -------------
__global__ __launch_bounds__(256) void mlstep_b(
    const float* __restrict__ D_ws, const float* __restrict__ b3,
    const float* __restrict__ uprev, float* __restrict__ uout,
    int b0, int BC) {
  int idx = blockIdx.x * 256 + threadIdx.x;
  int bl = idx >> 14;
  int rem = idx & (SPAT - 1);
  int y = rem >> 7, x = rem & NMASK;
  float acc = b3[0];
#pragma unroll
  for (int t = 0; t < 9; ++t) {
    int yy = (y + t / 3 - 1) & NMASK;
    int xx = (x + t % 3 - 1) & NMASK;
    acc += D_ws[((size_t)(t * BC + bl) << 14) + (yy << 7) + xx];
  }
  size_t g = ((size_t)(b0 + bl) << 14) + rem;
  uout[g] = uprev[g] + acc;
}

// ---------------- routing scores ----------------------------------------
__global__ void scores_kernel(float* __restrict__ s) {
  int i = blockIdx.x * 256 + threadIdx.x;
  if (i < 8 * BS * 2) {
    int it = i >> 6;
    int k = i & 1;
    bool ml = (it & 3) == 3;
    s[i] = ml ? (float)k : (float)(1 - k);
  }
}

extern "C" void kernel_launch(void* const* d_in, const int* in_sizes, int n_in,
                              void* d_out, int out_size, void* d_ws,
                              size_t ws_size, hipStream_t stream) {
  (void)in_sizes; (void)n_in; (void)out_size;
  const float* f  = (const float*)d_in[0];
  const float* u0 = (const float*)d_in[1];
  const float* w1 = (const float*)d_in[2];
  const float* b1 = (const float*)d_in[3];
  const float* w2 = (const float*)d_in[4];
  const float* b2 = (const float*)d_in[5];
  const float* w3 = (const float*)d_in[6];
  const float* b3 = (const float*)d_in[7];

  float* preds  = (float*)d_out;                  // [8][32][128][128]
  float* scores = preds + (size_t)8 * BS * SPAT;  // [8][32][2]

  short* w2b = (short*)d_ws;                       // 73728 B
  short* w1a = w2b + 36864;                        // 2048 B
  short* w3b = w1a + 1024;                         // 4096 B
  float* res_ws = (float*)(w3b + 2048);            // 2 MB
  float* D_ws = res_ws + (size_t)BS * SPAT;        // 9*BC*64KB
  size_t fixed = (size_t)(36864 + 1024 + 2048) * 2 + (size_t)BS * SPAT * 4;
  size_t avail = ws_size > fixed ? ws_size - fixed : 0;
  int BC = 32;
  while (BC > 1 && (size_t)BC * ((size_t)9 * SPAT * 4) > avail) BC >>= 1;

  prep_kernel<<<156, 256, 0, stream>>>(w2, w1, w3, w2b, w1a, w3b);

  for (int p = 0; p < 2; ++p) {
    int it = 4 * p;
    const float* up = (p == 0) ? u0 : preds + (size_t)3 * BS * SPAT;
    float* u1o = preds + (size_t)(it + 0) * BS * SPAT;
    float* u2o = preds + (size_t)(it + 1) * BS * SPAT;
    float* u3o = preds + (size_t)(it + 2) * BS * SPAT;
    float* umo = preds + (size_t)(it + 3) * BS * SPAT;
    jac3_kernel<<<BS * 64, 256, 0, stream>>>(up, f, u1o, u2o, u3o, res_ws);
    for (int b0 = 0; b0 < BS; b0 += BC) {
      mlstep_a<<<BC * 64, 512, 0, stream>>>(res_ws, w1a, b1, w2b, b2, w3b,
                                            D_ws, b0, BC);
      mlstep_b<<<BC * SPAT / 256, 256, 0, stream>>>(D_ws, b3, u3o, umo, b0, BC);
    }
  }
  scores_kernel<<<2, 256, 0, stream>>>(scores);
}

// Round 6
// 142.639 us; speedup vs baseline: 25.2803x; 1.0930x over previous
//
#include <hip/hip_runtime.h>
#include <hip/hip_bf16.h>

#define BS 32
#define SPAT 16384
#define NMASK 127

using short8  = __attribute__((ext_vector_type(8))) short;
using short4v = __attribute__((ext_vector_type(4))) short;
using f32x16  = __attribute__((ext_vector_type(16))) float;
using f32x4   = __attribute__((ext_vector_type(4))) float;

__device__ inline short f2bf(float f) {
  __hip_bfloat16 h = __float2bfloat16(f);
  return *reinterpret_cast<short*>(&h);
}

// ---------------- weight repack ----------------------------------------
// w2b[cob][t][c][lh][l31][8]: lane-coalesced MFMA A-fragments (1KB/fragment)
// w1a[ch][16]; w3b[c][lh][l31=t][8] lane-coalesced
__global__ __launch_bounds__(256) void prep_kernel(
    const float* __restrict__ w2, const float* __restrict__ w1,
    const float* __restrict__ w3, short* __restrict__ w2b,
    short* __restrict__ w1a, short* __restrict__ w3b) {
  int idx = blockIdx.x * 256 + threadIdx.x;
  if (idx < 36864) {
    int cob = idx / 18432, r = idx % 18432;
    int t = r / 2048, r2 = r & 2047;
    int c = r2 >> 9, lh = (r2 >> 8) & 1, l31 = (r2 >> 3) & 31, j = r2 & 7;
    int co = cob * 32 + l31, ci = c * 16 + 8 * lh + j;
    w2b[idx] = f2bf(w2[(co * 64 + ci) * 9 + t]);
  } else if (idx < 37888) {
    int j = idx - 36864;
    int ch = j >> 4, t = j & 15;
    w1a[j] = (t < 9) ? f2bf(w1[ch * 9 + t]) : (short)0;
  } else if (idx < 39936) {
    int q = idx - 37888;
    int c = q >> 9, lh = (q >> 8) & 1, l31 = (q >> 3) & 31, j = q & 7;
    int t = l31, ci = c * 16 + 8 * lh + j;
    w3b[q] = (t < 9) ? f2bf(w3[ci * 9 + t]) : (short)0;
  }
}

// ---------------- fused 3x Jacobi + residual ---------------------------
__global__ __launch_bounds__(256) void jac3_kernel(
    const float* __restrict__ uin, const float* __restrict__ f,
    float* __restrict__ u1o, float* __restrict__ u2o,
    float* __restrict__ u3o, float* __restrict__ res_ws) {
  __shared__ float As[576];   // 24x24
  __shared__ float Bs[484];   // 22x22
  __shared__ float Fs[484];   // 22x22, coords = (y0-3+i, x0-3+j)
  int tid = threadIdx.x;
  int bl = blockIdx.x >> 6, tile = blockIdx.x & 63;
  int y0 = (tile >> 3) << 4, x0 = (tile & 7) << 4;
  const float* ub = uin + ((size_t)bl << 14);
  const float* fb = f + ((size_t)bl << 14);
  for (int i = tid; i < 576; i += 256) {
    int uy = i / 24, ux = i % 24;
    As[i] = ub[(((y0 + uy - 4) & NMASK) << 7) + ((x0 + ux - 4) & NMASK)];
  }
  for (int i = tid; i < 484; i += 256) {
    int uy = i / 22, ux = i % 22;
    Fs[i] = fb[(((y0 + uy - 3) & NMASK) << 7) + ((x0 + ux - 3) & NMASK)];
  }
  __syncthreads();
  for (int i = tid; i < 484; i += 256) {
    int yy = i / 22, xx = i % 22;
    float uc = As[(yy + 1) * 24 + xx + 1];
    float ns = As[yy * 24 + xx + 1] + As[(yy + 2) * 24 + xx + 1]
             + As[(yy + 1) * 24 + xx] + As[(yy + 1) * 24 + xx + 2];
    Bs[i] = uc + Fs[i] * (1.f / 65536.f) + (ns - 4.f * uc) * 0.25f;
  }
  __syncthreads();
  {
    int y = tid >> 4, x = tid & 15;
    u1o[((size_t)bl << 14) + ((y0 + y) << 7) + x0 + x] = Bs[(y + 3) * 22 + x + 3];
  }
  for (int i = tid; i < 400; i += 256) {
    int yy = i / 20, xx = i % 20;
    float uc = Bs[(yy + 1) * 22 + xx + 1];
    float ns = Bs[yy * 22 + xx + 1] + Bs[(yy + 2) * 22 + xx + 1]
             + Bs[(yy + 1) * 22 + xx] + Bs[(yy + 1) * 22 + xx + 2];
    As[i] = uc + Fs[(yy + 1) * 22 + xx + 1] * (1.f / 65536.f)
          + (ns - 4.f * uc) * 0.25f;
  }
  __syncthreads();
  {
    int y = tid >> 4, x = tid & 15;
    u2o[((size_t)bl << 14) + ((y0 + y) << 7) + x0 + x] = As[(y + 2) * 20 + x + 2];
  }
  for (int i = tid; i < 324; i += 256) {
    int yy = i / 18, xx = i % 18;
    float uc = As[(yy + 1) * 20 + xx + 1];
    float ns = As[yy * 20 + xx + 1] + As[(yy + 2) * 20 + xx + 1]
             + As[(yy + 1) * 20 + xx] + As[(yy + 1) * 20 + xx + 2];
    Bs[i] = uc + Fs[(yy + 2) * 22 + xx + 2] * (1.f / 65536.f)
          + (ns - 4.f * uc) * 0.25f;
  }
  __syncthreads();
  {
    int y = tid >> 4, x = tid & 15;
    size_t gi = ((size_t)bl << 14) + ((y0 + y) << 7) + x0 + x;
    float uc = Bs[(y + 1) * 18 + x + 1];
    u3o[gi] = uc;
    float ns = Bs[y * 18 + x + 1] + Bs[(y + 2) * 18 + x + 1]
             + Bs[(y + 1) * 18 + x] + Bs[(y + 1) * 18 + x + 2];
    res_ws[gi] = Fs[(y + 3) * 22 + x + 3] + (ns - 4.f * uc) * 16384.f;
  }
}

// ---------------- fused conv1 + conv2 + depthwise-conv3 (all MFMA) -----
// 512 threads (8 waves); wave wv owns px [wv*32, wv*32+32), all 64 co.
// LDS = h1g 41472B + res_s 1600B = 43072B -> 3 blocks/CU.
__global__ __launch_bounds__(512, 6) void mlstep_a(
    const float* __restrict__ res_ws,
    const short* __restrict__ w1a, const float* __restrict__ b1v,
    const short* __restrict__ w2b, const float* __restrict__ b2v,
    const short* __restrict__ w3b, float* __restrict__ D_ws,
    int b0, int BC) {
  __shared__ __align__(16) short h1g[8 * 324 * 8];  // reused as h2t [8][256][8]
  __shared__ float res_s[400];                      // 20x20, halo 2
  int tid = threadIdx.x;
  int bl = blockIdx.x >> 6;
  int tile = blockIdx.x & 63;
  int y0 = (tile >> 3) << 4, x0 = (tile & 7) << 4;
  const float* rb = res_ws + ((size_t)(b0 + bl) << 14);

  if (tid < 400) {
    int ry = tid / 20, rx = tid % 20;
    res_s[tid] = rb[(((y0 + ry - 2) & NMASK) << 7) + ((x0 + rx - 2) & NMASK)];
  }
  __syncthreads();

  int lane = tid & 63, wv = tid >> 6;
  int l31 = lane & 31, lh = lane >> 5;

  // conv1 via MFMA (11 pos-groups over 8 waves); B-frag built in registers
  {
    short8 a1lo = *reinterpret_cast<const short8*>(&w1a[l31 * 16 + 8 * lh]);
    short8 a1hi = *reinterpret_cast<const short8*>(&w1a[(32 + l31) * 16 + 8 * lh]);
    for (int g = wv; g < 11; g += 8) {
      int pos = g * 32 + l31;
      short8 bf = {};
      if (pos < 324) {
        int yy = pos / 18, xx = pos % 18;
        if (lh == 0) {
#pragma unroll
          for (int t = 0; t < 8; ++t)
            bf[t] = f2bf(res_s[(yy + t / 3) * 20 + xx + t % 3]);
        } else {
          bf[0] = f2bf(res_s[(yy + 2) * 20 + xx + 2]);
        }
      }
      f32x16 acc0, acc1;
#pragma unroll
      for (int r = 0; r < 16; ++r) { acc0[r] = 0.f; acc1[r] = 0.f; }
      acc0 = __builtin_amdgcn_mfma_f32_32x32x16_bf16(a1lo, bf, acc0, 0, 0, 0);
      acc1 = __builtin_amdgcn_mfma_f32_32x32x16_bf16(a1hi, bf, acc1, 0, 0, 0);
      if (pos < 324) {
#pragma unroll
        for (int q = 0; q < 4; ++q) {
          f32x4 bv0 = *reinterpret_cast<const f32x4*>(&b1v[8 * q + 4 * lh]);
          f32x4 bv1 = *reinterpret_cast<const f32x4*>(&b1v[32 + 8 * q + 4 * lh]);
          short4v o0, o1;
#pragma unroll
          for (int j = 0; j < 4; ++j) {
            float v0 = acc0[4 * q + j] + bv0[j];
            float v1 = acc1[4 * q + j] + bv1[j];
            o0[j] = f2bf(v0 > 0.f ? v0 : 0.f);
            o1[j] = f2bf(v1 > 0.f ? v1 : 0.f);
          }
          *reinterpret_cast<short4v*>(
              (char*)h1g + (q * 324 + pos) * 16 + 8 * lh) = o0;
          *reinterpret_cast<short4v*>(
              (char*)h1g + ((4 + q) * 324 + pos) * 16 + 8 * lh) = o1;
        }
      }
    }
  }
  __syncthreads();

  // conv2: coalesced 1KB A-fragment loads, conflict-light LDS B-reads
  int px = (wv << 5) + l31;
  {
    int pos0 = (px >> 4) * 18 + (px & 15);
    const char* hb = (const char*)h1g + lh * 5184 + pos0 * 16;
    const char* wb = (const char*)w2b + lane * 16;
    f32x16 acc0, acc1;
#pragma unroll
    for (int r = 0; r < 16; ++r) { acc0[r] = 0.f; acc1[r] = 0.f; }
#pragma unroll
    for (int t = 0; t < 9; ++t) {
#pragma unroll
      for (int c = 0; c < 4; ++c) {
        short8 af0 = *reinterpret_cast<const short8*>(wb + (t * 4 + c) * 1024);
        short8 af1 = *reinterpret_cast<const short8*>(
            wb + ((9 + t) * 4 + c) * 1024);
        short8 bf = *reinterpret_cast<const short8*>(
            hb + c * 10368 + ((t / 3) * 18 + (t % 3)) * 16);
        acc0 = __builtin_amdgcn_mfma_f32_32x32x16_bf16(af0, bf, acc0, 0, 0, 0);
        acc1 = __builtin_amdgcn_mfma_f32_32x32x16_bf16(af1, bf, acc1, 0, 0, 0);
      }
    }
    __syncthreads();  // conv2 reads of h1g done -> reuse as h2t

    // h2 (ReLU+bias, bf16) -> LDS cg-major [cg][px][8]
    short* h2t = h1g;
#pragma unroll
    for (int cb = 0; cb < 2; ++cb) {
      const f32x16& a = cb ? acc1 : acc0;
#pragma unroll
      for (int q = 0; q < 4; ++q) {
        int ch0 = cb * 32 + 8 * q + 4 * lh;
        f32x4 bv = *reinterpret_cast<const f32x4*>(&b2v[ch0]);
        short4v o;
#pragma unroll
        for (int j = 0; j < 4; ++j) {
          float v = a[4 * q + j] + bv[j];
          o[j] = f2bf(v > 0.f ? v : 0.f);
        }
        int cg = cb * 4 + q;
        *reinterpret_cast<short4v*>(&h2t[(cg * 256 + px) * 8 + 4 * lh]) = o;
      }
    }
    // depthwise conv3 — wave-local px, no barrier needed
    f32x16 d;
#pragma unroll
    for (int r = 0; r < 16; ++r) d[r] = 0.f;
#pragma unroll
    for (int c = 0; c < 4; ++c) {
      short8 af3 = *reinterpret_cast<const short8*>(
          (const char*)w3b + c * 1024 + lane * 16);
      short8 bf = *reinterpret_cast<const short8*>(
          (const char*)h2t + ((2 * c + lh) * 256 + px) * 16);
      d = __builtin_amdgcn_mfma_f32_32x32x16_bf16(af3, bf, d, 0, 0, 0);
    }
    int gpx = ((y0 + (px >> 4)) << 7) + x0 + (px & 15);
    if (lh == 0) {
#pragma unroll
      for (int r = 0; r < 4; ++r)
        D_ws[((size_t)(r * BC + bl) << 14) + gpx] = d[r];
      D_ws[((size_t)(8 * BC + bl) << 14) + gpx] = d[4];
    } else {
#pragma unroll
      for (int r = 0; r < 4; ++r)
        D_ws[((size_t)((4 + r) * BC + bl) << 14) + gpx] = d[r];
    }
  }
}

// ---------------- conv3 shift-sum + u update (memory-bound) -------------
__global__ __launch_bounds__(256) void mlstep_b(
    const float* __restrict__ D_ws, const float* __restrict__ b3,
    const float* __restrict__ uprev, float* __restrict__ uout,
    int b0, int BC) {
  int idx = blockIdx.x * 256 + threadIdx.x;
  int bl = idx >> 14;
  int rem = idx & (SPAT - 1);
  int y = rem >> 7, x = rem & NMASK;
  float acc = b3[0];
#pragma unroll
  for (int t = 0; t < 9; ++t) {
    int yy = (y + t / 3 - 1) & NMASK;
    int xx = (x + t % 3 - 1) & NMASK;
    acc += D_ws[((size_t)(t * BC + bl) << 14) + (yy << 7) + xx];
  }
  size_t g = ((size_t)(b0 + bl) << 14) + rem;
  uout[g] = uprev[g] + acc;
}

// ---------------- routing scores ----------------------------------------
__global__ void scores_kernel(float* __restrict__ s) {
  int i = blockIdx.x * 256 + threadIdx.x;
  if (i < 8 * BS * 2) {
    int it = i >> 6;
    int k = i & 1;
    bool ml = (it & 3) == 3;
    s[i] = ml ? (float)k : (float)(1 - k);
  }
}

extern "C" void kernel_launch(void* const* d_in, const int* in_sizes, int n_in,
                              void* d_out, int out_size, void* d_ws,
                              size_t ws_size, hipStream_t stream) {
  (void)in_sizes; (void)n_in; (void)out_size;
  const float* f  = (const float*)d_in[0];
  const float* u0 = (const float*)d_in[1];
  const float* w1 = (const float*)d_in[2];
  const float* b1 = (const float*)d_in[3];
  const float* w2 = (const float*)d_in[4];
  const float* b2 = (const float*)d_in[5];
  const float* w3 = (const float*)d_in[6];
  const float* b3 = (const float*)d_in[7];

  float* preds  = (float*)d_out;                  // [8][32][128][128]
  float* scores = preds + (size_t)8 * BS * SPAT;  // [8][32][2]

  short* w2b = (short*)d_ws;                       // 73728 B
  short* w1a = w2b + 36864;                        // 2048 B
  short* w3b = w1a + 1024;                         // 4096 B
  float* res_ws = (float*)(w3b + 2048);            // 2 MB
  float* D_ws = res_ws + (size_t)BS * SPAT;        // 9*BC*64KB
  size_t fixed = (size_t)(36864 + 1024 + 2048) * 2 + (size_t)BS * SPAT * 4;
  size_t avail = ws_size > fixed ? ws_size - fixed : 0;
  int BC = 32;
  while (BC > 1 && (size_t)BC * ((size_t)9 * SPAT * 4) > avail) BC >>= 1;

  prep_kernel<<<156, 256, 0, stream>>>(w2, w1, w3, w2b, w1a, w3b);

  for (int p = 0; p < 2; ++p) {
    int it = 4 * p;
    const float* up = (p == 0) ? u0 : preds + (size_t)3 * BS * SPAT;
    float* u1o = preds + (size_t)(it + 0) * BS * SPAT;
    float* u2o = preds + (size_t)(it + 1) * BS * SPAT;
    float* u3o = preds + (size_t)(it + 2) * BS * SPAT;
    float* umo = preds + (size_t)(it + 3) * BS * SPAT;
    jac3_kernel<<<BS * 64, 256, 0, stream>>>(up, f, u1o, u2o, u3o, res_ws);
    for (int b0 = 0; b0 < BS; b0 += BC) {
      mlstep_a<<<BC * 64, 512, 0, stream>>>(res_ws, w1a, b1, w2b, b2, w3b,
                                            D_ws, b0, BC);
      mlstep_b<<<BC * SPAT / 256, 256, 0, stream>>>(D_ws, b3, u3o, umo, b0, BC);
    }
  }
  scores_kernel<<<2, 256, 0, stream>>>(scores);
}

// Round 7
// 137.090 us; speedup vs baseline: 26.3034x; 1.0405x over previous
//
#include <hip/hip_runtime.h>
#include <hip/hip_bf16.h>

#define BS 32
#define SPAT 16384
#define NMASK 127

using short8  = __attribute__((ext_vector_type(8))) short;
using short4v = __attribute__((ext_vector_type(4))) short;
using f32x16  = __attribute__((ext_vector_type(16))) float;
using f32x4   = __attribute__((ext_vector_type(4))) float;

__device__ inline short f2bf(float f) {
  __hip_bfloat16 h = __float2bfloat16(f);
  return *reinterpret_cast<short*>(&h);
}

// ---------------- weight repack ----------------------------------------
// w2b[cob][t][c][lh][l31][8]: lane-coalesced MFMA A-fragments (1KB/fragment)
// w1a[ch][16]; w3b[c][lh][l31=t][8] lane-coalesced
__global__ __launch_bounds__(256) void prep_kernel(
    const float* __restrict__ w2, const float* __restrict__ w1,
    const float* __restrict__ w3, short* __restrict__ w2b,
    short* __restrict__ w1a, short* __restrict__ w3b) {
  int idx = blockIdx.x * 256 + threadIdx.x;
  if (idx < 36864) {
    int cob = idx / 18432, r = idx % 18432;
    int t = r / 2048, r2 = r & 2047;
    int c = r2 >> 9, lh = (r2 >> 8) & 1, l31 = (r2 >> 3) & 31, j = r2 & 7;
    int co = cob * 32 + l31, ci = c * 16 + 8 * lh + j;
    w2b[idx] = f2bf(w2[(co * 64 + ci) * 9 + t]);
  } else if (idx < 37888) {
    int j = idx - 36864;
    int ch = j >> 4, t = j & 15;
    w1a[j] = (t < 9) ? f2bf(w1[ch * 9 + t]) : (short)0;
  } else if (idx < 39936) {
    int q = idx - 37888;
    int c = q >> 9, lh = (q >> 8) & 1, l31 = (q >> 3) & 31, j = q & 7;
    int t = l31, ci = c * 16 + 8 * lh + j;
    w3b[q] = (t < 9) ? f2bf(w3[ci * 9 + t]) : (short)0;
  }
}

// ---------------- fused 3x Jacobi + residual ---------------------------
__global__ __launch_bounds__(256) void jac3_kernel(
    const float* __restrict__ uin, const float* __restrict__ f,
    float* __restrict__ u1o, float* __restrict__ u2o,
    float* __restrict__ u3o, float* __restrict__ res_ws) {
  __shared__ float As[576];   // 24x24
  __shared__ float Bs[484];   // 22x22
  __shared__ float Fs[484];   // 22x22, coords = (y0-3+i, x0-3+j)
  int tid = threadIdx.x;
  int bl = blockIdx.x >> 6, tile = blockIdx.x & 63;
  int y0 = (tile >> 3) << 4, x0 = (tile & 7) << 4;
  const float* ub = uin + ((size_t)bl << 14);
  const float* fb = f + ((size_t)bl << 14);
  for (int i = tid; i < 576; i += 256) {
    int uy = i / 24, ux = i % 24;
    As[i] = ub[(((y0 + uy - 4) & NMASK) << 7) + ((x0 + ux - 4) & NMASK)];
  }
  for (int i = tid; i < 484; i += 256) {
    int uy = i / 22, ux = i % 22;
    Fs[i] = fb[(((y0 + uy - 3) & NMASK) << 7) + ((x0 + ux - 3) & NMASK)];
  }
  __syncthreads();
  for (int i = tid; i < 484; i += 256) {
    int yy = i / 22, xx = i % 22;
    float uc = As[(yy + 1) * 24 + xx + 1];
    float ns = As[yy * 24 + xx + 1] + As[(yy + 2) * 24 + xx + 1]
             + As[(yy + 1) * 24 + xx] + As[(yy + 1) * 24 + xx + 2];
    Bs[i] = uc + Fs[i] * (1.f / 65536.f) + (ns - 4.f * uc) * 0.25f;
  }
  __syncthreads();
  {
    int y = tid >> 4, x = tid & 15;
    u1o[((size_t)bl << 14) + ((y0 + y) << 7) + x0 + x] = Bs[(y + 3) * 22 + x + 3];
  }
  for (int i = tid; i < 400; i += 256) {
    int yy = i / 20, xx = i % 20;
    float uc = Bs[(yy + 1) * 22 + xx + 1];
    float ns = Bs[yy * 22 + xx + 1] + Bs[(yy + 2) * 22 + xx + 1]
             + Bs[(yy + 1) * 22 + xx] + Bs[(yy + 1) * 22 + xx + 2];
    As[i] = uc + Fs[(yy + 1) * 22 + xx + 1] * (1.f / 65536.f)
          + (ns - 4.f * uc) * 0.25f;
  }
  __syncthreads();
  {
    int y = tid >> 4, x = tid & 15;
    u2o[((size_t)bl << 14) + ((y0 + y) << 7) + x0 + x] = As[(y + 2) * 20 + x + 2];
  }
  for (int i = tid; i < 324; i += 256) {
    int yy = i / 18, xx = i % 18;
    float uc = As[(yy + 1) * 20 + xx + 1];
    float ns = As[yy * 20 + xx + 1] + As[(yy + 2) * 20 + xx + 1]
             + As[(yy + 1) * 20 + xx] + As[(yy + 1) * 20 + xx + 2];
    Bs[i] = uc + Fs[(yy + 2) * 22 + xx + 2] * (1.f / 65536.f)
          + (ns - 4.f * uc) * 0.25f;
  }
  __syncthreads();
  {
    int y = tid >> 4, x = tid & 15;
    size_t gi = ((size_t)bl << 14) + ((y0 + y) << 7) + x0 + x;
    float uc = Bs[(y + 1) * 18 + x + 1];
    u3o[gi] = uc;
    float ns = Bs[y * 18 + x + 1] + Bs[(y + 2) * 18 + x + 1]
             + Bs[(y + 1) * 18 + x] + Bs[(y + 1) * 18 + x + 2];
    res_ws[gi] = Fs[(y + 3) * 22 + x + 3] + (ns - 4.f * uc) * 16384.f;
  }
}

// ---------------- fused conv1 + conv2 + depthwise-conv3 (all MFMA) -----
// 256 threads (4 waves); wave wv owns px [wv*64, wv*64+64) (nt=2), all 64 co.
// Each A-fragment pair feeds 4 MFMAs -> A global traffic halved vs 8-wave.
__global__ __launch_bounds__(256, 3) void mlstep_a(
    const float* __restrict__ res_ws,
    const short* __restrict__ w1a, const float* __restrict__ b1v,
    const short* __restrict__ w2b, const float* __restrict__ b2v,
    const short* __restrict__ w3b, float* __restrict__ D_ws,
    int b0, int BC) {
  __shared__ __align__(16) short h1g[8 * 324 * 8];  // reused as h2t [8][256][8]
  __shared__ float res_s[400];                      // 20x20, halo 2
  int tid = threadIdx.x;
  int bl = blockIdx.x >> 6;
  int tile = blockIdx.x & 63;
  int y0 = (tile >> 3) << 4, x0 = (tile & 7) << 4;
  const float* rb = res_ws + ((size_t)(b0 + bl) << 14);

  for (int i = tid; i < 400; i += 256) {
    int ry = i / 20, rx = i % 20;
    res_s[i] = rb[(((y0 + ry - 2) & NMASK) << 7) + ((x0 + rx - 2) & NMASK)];
  }
  __syncthreads();

  int lane = tid & 63, wv = tid >> 6;  // wv in 0..3
  int l31 = lane & 31, lh = lane >> 5;

  // conv1 via MFMA (11 pos-groups over 4 waves); B-frag built in registers
  {
    short8 a1lo = *reinterpret_cast<const short8*>(&w1a[l31 * 16 + 8 * lh]);
    short8 a1hi = *reinterpret_cast<const short8*>(&w1a[(32 + l31) * 16 + 8 * lh]);
    for (int g = wv; g < 11; g += 4) {
      int pos = g * 32 + l31;
      short8 bf = {};
      if (pos < 324) {
        int yy = pos / 18, xx = pos % 18;
        if (lh == 0) {
#pragma unroll
          for (int t = 0; t < 8; ++t)
            bf[t] = f2bf(res_s[(yy + t / 3) * 20 + xx + t % 3]);
        } else {
          bf[0] = f2bf(res_s[(yy + 2) * 20 + xx + 2]);
        }
      }
      f32x16 acc0, acc1;
#pragma unroll
      for (int r = 0; r < 16; ++r) { acc0[r] = 0.f; acc1[r] = 0.f; }
      acc0 = __builtin_amdgcn_mfma_f32_32x32x16_bf16(a1lo, bf, acc0, 0, 0, 0);
      acc1 = __builtin_amdgcn_mfma_f32_32x32x16_bf16(a1hi, bf, acc1, 0, 0, 0);
      if (pos < 324) {
#pragma unroll
        for (int q = 0; q < 4; ++q) {
          f32x4 bv0 = *reinterpret_cast<const f32x4*>(&b1v[8 * q + 4 * lh]);
          f32x4 bv1 = *reinterpret_cast<const f32x4*>(&b1v[32 + 8 * q + 4 * lh]);
          short4v o0, o1;
#pragma unroll
          for (int j = 0; j < 4; ++j) {
            float v0 = acc0[4 * q + j] + bv0[j];
            float v1 = acc1[4 * q + j] + bv1[j];
            o0[j] = f2bf(v0 > 0.f ? v0 : 0.f);
            o1[j] = f2bf(v1 > 0.f ? v1 : 0.f);
          }
          *reinterpret_cast<short4v*>(
              (char*)h1g + (q * 324 + pos) * 16 + 8 * lh) = o0;
          *reinterpret_cast<short4v*>(
              (char*)h1g + ((4 + q) * 324 + pos) * 16 + 8 * lh) = o1;
        }
      }
    }
  }
  __syncthreads();

  // conv2: 2 cob x 2 nt per wave; A-frags reused across both nt
  {
    const char* hb[2];
#pragma unroll
    for (int nt = 0; nt < 2; ++nt) {
      int px = (wv << 6) + (nt << 5) + l31;
      int pos0 = (px >> 4) * 18 + (px & 15);
      hb[nt] = (const char*)h1g + lh * 5184 + pos0 * 16;
    }
    const char* wb = (const char*)w2b + lane * 16;
    f32x16 acc[2][2];  // [cob][nt]
#pragma unroll
    for (int cb = 0; cb < 2; ++cb)
#pragma unroll
      for (int nt = 0; nt < 2; ++nt)
#pragma unroll
        for (int r = 0; r < 16; ++r) acc[cb][nt][r] = 0.f;
#pragma unroll
    for (int t = 0; t < 9; ++t) {
#pragma unroll
      for (int c = 0; c < 4; ++c) {
        short8 af0 = *reinterpret_cast<const short8*>(wb + (t * 4 + c) * 1024);
        short8 af1 = *reinterpret_cast<const short8*>(
            wb + ((9 + t) * 4 + c) * 1024);
        int toff = ((t / 3) * 18 + (t % 3)) * 16;
#pragma unroll
        for (int nt = 0; nt < 2; ++nt) {
          short8 bf = *reinterpret_cast<const short8*>(
              hb[nt] + c * 10368 + toff);
          acc[0][nt] = __builtin_amdgcn_mfma_f32_32x32x16_bf16(af0, bf,
                                                               acc[0][nt], 0, 0, 0);
          acc[1][nt] = __builtin_amdgcn_mfma_f32_32x32x16_bf16(af1, bf,
                                                               acc[1][nt], 0, 0, 0);
        }
      }
    }
    __syncthreads();  // conv2 reads of h1g done -> reuse as h2t

    // h2 (ReLU+bias, bf16) -> LDS cg-major [cg][px][8]
    short* h2t = h1g;
#pragma unroll
    for (int nt = 0; nt < 2; ++nt) {
      int px = (wv << 6) + (nt << 5) + l31;
#pragma unroll
      for (int cb = 0; cb < 2; ++cb) {
#pragma unroll
        for (int q = 0; q < 4; ++q) {
          int ch0 = cb * 32 + 8 * q + 4 * lh;
          f32x4 bv = *reinterpret_cast<const f32x4*>(&b2v[ch0]);
          short4v o;
#pragma unroll
          for (int j = 0; j < 4; ++j) {
            float v = acc[cb][nt][4 * q + j] + bv[j];
            o[j] = f2bf(v > 0.f ? v : 0.f);
          }
          int cg = cb * 4 + q;
          *reinterpret_cast<short4v*>(&h2t[(cg * 256 + px) * 8 + 4 * lh]) = o;
        }
      }
    }
    // depthwise conv3 — wave-local px, no barrier needed
    short8 af3[4];
#pragma unroll
    for (int c = 0; c < 4; ++c)
      af3[c] = *reinterpret_cast<const short8*>(
          (const char*)w3b + c * 1024 + lane * 16);
#pragma unroll
    for (int nt = 0; nt < 2; ++nt) {
      int pxb = (wv << 6) + (nt << 5);
      f32x16 d;
#pragma unroll
      for (int r = 0; r < 16; ++r) d[r] = 0.f;
#pragma unroll
      for (int c = 0; c < 4; ++c) {
        short8 bf = *reinterpret_cast<const short8*>(
            (const char*)h2t + ((2 * c + lh) * 256 + pxb + l31) * 16);
        d = __builtin_amdgcn_mfma_f32_32x32x16_bf16(af3[c], bf, d, 0, 0, 0);
      }
      int px = pxb + l31;
      int gpx = ((y0 + (px >> 4)) << 7) + x0 + (px & 15);
      if (lh == 0) {
#pragma unroll
        for (int r = 0; r < 4; ++r)
          D_ws[((size_t)(r * BC + bl) << 14) + gpx] = d[r];
        D_ws[((size_t)(8 * BC + bl) << 14) + gpx] = d[4];
      } else {
#pragma unroll
        for (int r = 0; r < 4; ++r)
          D_ws[((size_t)((4 + r) * BC + bl) << 14) + gpx] = d[r];
      }
    }
  }
}

// ---------------- conv3 shift-sum + u update (memory-bound) -------------
__global__ __launch_bounds__(256) void mlstep_b(
    const float* __restrict__ D_ws, const float* __restrict__ b3,
    const float* __restrict__ uprev, float* __restrict__ uout,
    int b0, int BC) {
  int idx = blockIdx.x * 256 + threadIdx.x;
  int bl = idx >> 14;
  int rem = idx & (SPAT - 1);
  int y = rem >> 7, x = rem & NMASK;
  float acc = b3[0];
#pragma unroll
  for (int t = 0; t < 9; ++t) {
    int yy = (y + t / 3 - 1) & NMASK;
    int xx = (x + t % 3 - 1) & NMASK;
    acc += D_ws[((size_t)(t * BC + bl) << 14) + (yy << 7) + xx];
  }
  size_t g = ((size_t)(b0 + bl) << 14) + rem;
  uout[g] = uprev[g] + acc;
}

// ---------------- routing scores ----------------------------------------
__global__ void scores_kernel(float* __restrict__ s) {
  int i = blockIdx.x * 256 + threadIdx.x;
  if (i < 8 * BS * 2) {
    int it = i >> 6;
    int k = i & 1;
    bool ml = (it & 3) == 3;
    s[i] = ml ? (float)k : (float)(1 - k);
  }
}

extern "C" void kernel_launch(void* const* d_in, const int* in_sizes, int n_in,
                              void* d_out, int out_size, void* d_ws,
                              size_t ws_size, hipStream_t stream) {
  (void)in_sizes; (void)n_in; (void)out_size;
  const float* f  = (const float*)d_in[0];
  const float* u0 = (const float*)d_in[1];
  const float* w1 = (const float*)d_in[2];
  const float* b1 = (const float*)d_in[3];
  const float* w2 = (const float*)d_in[4];
  const float* b2 = (const float*)d_in[5];
  const float* w3 = (const float*)d_in[6];
  const float* b3 = (const float*)d_in[7];

  float* preds  = (float*)d_out;                  // [8][32][128][128]
  float* scores = preds + (size_t)8 * BS * SPAT;  // [8][32][2]

  short* w2b = (short*)d_ws;                       // 73728 B
  short* w1a = w2b + 36864;                        // 2048 B
  short* w3b = w1a + 1024;                         // 4096 B
  float* res_ws = (float*)(w3b + 2048);            // 2 MB
  float* D_ws = res_ws + (size_t)BS * SPAT;        // 9*BC*64KB
  size_t fixed = (size_t)(36864 + 1024 + 2048) * 2 + (size_t)BS * SPAT * 4;
  size_t avail = ws_size > fixed ? ws_size - fixed : 0;
  int BC = 32;
  while (BC > 1 && (size_t)BC * ((size_t)9 * SPAT * 4) > avail) BC >>= 1;

  prep_kernel<<<156, 256, 0, stream>>>(w2, w1, w3, w2b, w1a, w3b);

  for (int p = 0; p < 2; ++p) {
    int it = 4 * p;
    const float* up = (p == 0) ? u0 : preds + (size_t)3 * BS * SPAT;
    float* u1o = preds + (size_t)(it + 0) * BS * SPAT;
    float* u2o = preds + (size_t)(it + 1) * BS * SPAT;
    float* u3o = preds + (size_t)(it + 2) * BS * SPAT;
    float* umo = preds + (size_t)(it + 3) * BS * SPAT;
    jac3_kernel<<<BS * 64, 256, 0, stream>>>(up, f, u1o, u2o, u3o, res_ws);
    for (int b0 = 0; b0 < BS; b0 += BC) {
      mlstep_a<<<BC * 64, 256, 0, stream>>>(res_ws, w1a, b1, w2b, b2, w3b,
                                            D_ws, b0, BC);
      mlstep_b<<<BC * SPAT / 256, 256, 0, stream>>>(D_ws, b3, u3o, umo, b0, BC);
    }
  }
  scores_kernel<<<2, 256, 0, stream>>>(scores);
}

// Round 8
// 125.170 us; speedup vs baseline: 28.8085x; 1.0952x over previous
//
#include <hip/hip_runtime.h>
#include <hip/hip_bf16.h>

#define BS 32
#define SPAT 16384
#define NMASK 127

using short8  = __attribute__((ext_vector_type(8))) short;
using short4v = __attribute__((ext_vector_type(4))) short;
using f32x16  = __attribute__((ext_vector_type(16))) float;
using f32x4   = __attribute__((ext_vector_type(4))) float;

__device__ inline short f2bf(float f) {
  __hip_bfloat16 h = __float2bfloat16(f);
  return *reinterpret_cast<short*>(&h);
}

// ---------------- weight repack ----------------------------------------
// w2b[cob][t][c][lh][l31][8]: lane-coalesced MFMA A-fragments (1KB/fragment)
// w1a[ch][16]; w3b[c][lh][l31=t][8] lane-coalesced
__global__ __launch_bounds__(256) void prep_kernel(
    const float* __restrict__ w2, const float* __restrict__ w1,
    const float* __restrict__ w3, short* __restrict__ w2b,
    short* __restrict__ w1a, short* __restrict__ w3b) {
  int idx = blockIdx.x * 256 + threadIdx.x;
  if (idx < 36864) {
    int cob = idx / 18432, r = idx % 18432;
    int t = r / 2048, r2 = r & 2047;
    int c = r2 >> 9, lh = (r2 >> 8) & 1, l31 = (r2 >> 3) & 31, j = r2 & 7;
    int co = cob * 32 + l31, ci = c * 16 + 8 * lh + j;
    w2b[idx] = f2bf(w2[(co * 64 + ci) * 9 + t]);
  } else if (idx < 37888) {
    int j = idx - 36864;
    int ch = j >> 4, t = j & 15;
    w1a[j] = (t < 9) ? f2bf(w1[ch * 9 + t]) : (short)0;
  } else if (idx < 39936) {
    int q = idx - 37888;
    int c = q >> 9, lh = (q >> 8) & 1, l31 = (q >> 3) & 31, j = q & 7;
    int t = l31, ci = c * 16 + 8 * lh + j;
    w3b[q] = (t < 9) ? f2bf(w3[ci * 9 + t]) : (short)0;
  }
}

// ---------------- fused 3x Jacobi + residual ---------------------------
__global__ __launch_bounds__(256) void jac3_kernel(
    const float* __restrict__ uin, const float* __restrict__ f,
    float* __restrict__ u1o, float* __restrict__ u2o,
    float* __restrict__ u3o, float* __restrict__ res_ws) {
  __shared__ float As[576];   // 24x24
  __shared__ float Bs[484];   // 22x22
  __shared__ float Fs[484];   // 22x22, coords = (y0-3+i, x0-3+j)
  int tid = threadIdx.x;
  int bl = blockIdx.x >> 6, tile = blockIdx.x & 63;
  int y0 = (tile >> 3) << 4, x0 = (tile & 7) << 4;
  const float* ub = uin + ((size_t)bl << 14);
  const float* fb = f + ((size_t)bl << 14);
  for (int i = tid; i < 576; i += 256) {
    int uy = i / 24, ux = i % 24;
    As[i] = ub[(((y0 + uy - 4) & NMASK) << 7) + ((x0 + ux - 4) & NMASK)];
  }
  for (int i = tid; i < 484; i += 256) {
    int uy = i / 22, ux = i % 22;
    Fs[i] = fb[(((y0 + uy - 3) & NMASK) << 7) + ((x0 + ux - 3) & NMASK)];
  }
  __syncthreads();
  for (int i = tid; i < 484; i += 256) {
    int yy = i / 22, xx = i % 22;
    float uc = As[(yy + 1) * 24 + xx + 1];
    float ns = As[yy * 24 + xx + 1] + As[(yy + 2) * 24 + xx + 1]
             + As[(yy + 1) * 24 + xx] + As[(yy + 1) * 24 + xx + 2];
    Bs[i] = uc + Fs[i] * (1.f / 65536.f) + (ns - 4.f * uc) * 0.25f;
  }
  __syncthreads();
  {
    int y = tid >> 4, x = tid & 15;
    u1o[((size_t)bl << 14) + ((y0 + y) << 7) + x0 + x] = Bs[(y + 3) * 22 + x + 3];
  }
  for (int i = tid; i < 400; i += 256) {
    int yy = i / 20, xx = i % 20;
    float uc = Bs[(yy + 1) * 22 + xx + 1];
    float ns = Bs[yy * 22 + xx + 1] + Bs[(yy + 2) * 22 + xx + 1]
             + Bs[(yy + 1) * 22 + xx] + Bs[(yy + 1) * 22 + xx + 2];
    As[i] = uc + Fs[(yy + 1) * 22 + xx + 1] * (1.f / 65536.f)
          + (ns - 4.f * uc) * 0.25f;
  }
  __syncthreads();
  {
    int y = tid >> 4, x = tid & 15;
    u2o[((size_t)bl << 14) + ((y0 + y) << 7) + x0 + x] = As[(y + 2) * 20 + x + 2];
  }
  for (int i = tid; i < 324; i += 256) {
    int yy = i / 18, xx = i % 18;
    float uc = As[(yy + 1) * 20 + xx + 1];
    float ns = As[yy * 20 + xx + 1] + As[(yy + 2) * 20 + xx + 1]
             + As[(yy + 1) * 20 + xx] + As[(yy + 1) * 20 + xx + 2];
    Bs[i] = uc + Fs[(yy + 2) * 22 + xx + 2] * (1.f / 65536.f)
          + (ns - 4.f * uc) * 0.25f;
  }
  __syncthreads();
  {
    int y = tid >> 4, x = tid & 15;
    size_t gi = ((size_t)bl << 14) + ((y0 + y) << 7) + x0 + x;
    float uc = Bs[(y + 1) * 18 + x + 1];
    u3o[gi] = uc;
    float ns = Bs[y * 18 + x + 1] + Bs[(y + 2) * 18 + x + 1]
             + Bs[(y + 1) * 18 + x] + Bs[(y + 1) * 18 + x + 2];
    res_ws[gi] = Fs[(y + 3) * 22 + x + 3] + (ns - 4.f * uc) * 16384.f;
  }
}

// ---------------- fused conv1 + conv2 + depthwise-conv3 (all MFMA) -----
// 256 threads (4 waves); wave wv owns px [wv*64, wv*64+64) (nt=2), all 64 co.
// conv2 weight loads are depth-1 software-pipelined over t; t=0 stage is
// issued before the conv1 barrier so its L2 latency hides under conv1.
__global__ __launch_bounds__(256, 3) void mlstep_a(
    const float* __restrict__ res_ws,
    const short* __restrict__ w1a, const float* __restrict__ b1v,
    const short* __restrict__ w2b, const float* __restrict__ b2v,
    const short* __restrict__ w3b, float* __restrict__ D_ws,
    int b0, int BC) {
  __shared__ __align__(16) short h1g[8 * 324 * 8];  // reused as h2t [8][256][8]
  __shared__ float res_s[400];                      // 20x20, halo 2
  int tid = threadIdx.x;
  int bl = blockIdx.x >> 6;
  int tile = blockIdx.x & 63;
  int y0 = (tile >> 3) << 4, x0 = (tile & 7) << 4;
  const float* rb = res_ws + ((size_t)(b0 + bl) << 14);

  for (int i = tid; i < 400; i += 256) {
    int ry = i / 20, rx = i % 20;
    res_s[i] = rb[(((y0 + ry - 2) & NMASK) << 7) + ((x0 + rx - 2) & NMASK)];
  }

  int lane = tid & 63, wv = tid >> 6;  // wv in 0..3
  int l31 = lane & 31, lh = lane >> 5;

  // ---- pre-issue conv2 t=0 weight stage (L2 latency hides under conv1) --
  const char* wb = (const char*)w2b + lane * 16;
  short8 a0[4], a1[4];
#pragma unroll
  for (int c = 0; c < 4; ++c) {
    a0[c] = *reinterpret_cast<const short8*>(wb + c * 1024);
    a1[c] = *reinterpret_cast<const short8*>(wb + (36 + c) * 1024);
  }
  __syncthreads();

  // conv1 via MFMA (11 pos-groups over 4 waves); B-frag built in registers
  {
    short8 a1lo = *reinterpret_cast<const short8*>(&w1a[l31 * 16 + 8 * lh]);
    short8 a1hi = *reinterpret_cast<const short8*>(&w1a[(32 + l31) * 16 + 8 * lh]);
    for (int g = wv; g < 11; g += 4) {
      int pos = g * 32 + l31;
      short8 bf = {};
      if (pos < 324) {
        int yy = pos / 18, xx = pos % 18;
        if (lh == 0) {
#pragma unroll
          for (int t = 0; t < 8; ++t)
            bf[t] = f2bf(res_s[(yy + t / 3) * 20 + xx + t % 3]);
        } else {
          bf[0] = f2bf(res_s[(yy + 2) * 20 + xx + 2]);
        }
      }
      f32x16 acc0, acc1;
#pragma unroll
      for (int r = 0; r < 16; ++r) { acc0[r] = 0.f; acc1[r] = 0.f; }
      acc0 = __builtin_amdgcn_mfma_f32_32x32x16_bf16(a1lo, bf, acc0, 0, 0, 0);
      acc1 = __builtin_amdgcn_mfma_f32_32x32x16_bf16(a1hi, bf, acc1, 0, 0, 0);
      if (pos < 324) {
#pragma unroll
        for (int q = 0; q < 4; ++q) {
          f32x4 bv0 = *reinterpret_cast<const f32x4*>(&b1v[8 * q + 4 * lh]);
          f32x4 bv1 = *reinterpret_cast<const f32x4*>(&b1v[32 + 8 * q + 4 * lh]);
          short4v o0, o1;
#pragma unroll
          for (int j = 0; j < 4; ++j) {
            float v0 = acc0[4 * q + j] + bv0[j];
            float v1 = acc1[4 * q + j] + bv1[j];
            o0[j] = f2bf(v0 > 0.f ? v0 : 0.f);
            o1[j] = f2bf(v1 > 0.f ? v1 : 0.f);
          }
          *reinterpret_cast<short4v*>(
              (char*)h1g + (q * 324 + pos) * 16 + 8 * lh) = o0;
          *reinterpret_cast<short4v*>(
              (char*)h1g + ((4 + q) * 324 + pos) * 16 + 8 * lh) = o1;
        }
      }
    }
  }
  __syncthreads();

  // conv2: 2 cob x 2 nt per wave; depth-1 weight pipeline over t
  {
    const char* hb[2];
#pragma unroll
    for (int nt = 0; nt < 2; ++nt) {
      int px = (wv << 6) + (nt << 5) + l31;
      int pos0 = (px >> 4) * 18 + (px & 15);
      hb[nt] = (const char*)h1g + lh * 5184 + pos0 * 16;
    }
    f32x16 acc[2][2];  // [cob][nt]
#pragma unroll
    for (int cb = 0; cb < 2; ++cb)
#pragma unroll
      for (int nt = 0; nt < 2; ++nt)
#pragma unroll
        for (int r = 0; r < 16; ++r) acc[cb][nt][r] = 0.f;
#pragma unroll
    for (int t = 0; t < 9; ++t) {
      short8 a0n[4], a1n[4];
      if (t < 8) {
#pragma unroll
        for (int c = 0; c < 4; ++c) {
          a0n[c] = *reinterpret_cast<const short8*>(
              wb + ((t + 1) * 4 + c) * 1024);
          a1n[c] = *reinterpret_cast<const short8*>(
              wb + ((10 + t) * 4 + c) * 1024);
        }
      }
      int toff = ((t / 3) * 18 + (t % 3)) * 16;
      __builtin_amdgcn_s_setprio(1);
#pragma unroll
      for (int c = 0; c < 4; ++c) {
#pragma unroll
        for (int nt = 0; nt < 2; ++nt) {
          short8 bf = *reinterpret_cast<const short8*>(
              hb[nt] + c * 10368 + toff);
          acc[0][nt] = __builtin_amdgcn_mfma_f32_32x32x16_bf16(a0[c], bf,
                                                               acc[0][nt], 0, 0, 0);
          acc[1][nt] = __builtin_amdgcn_mfma_f32_32x32x16_bf16(a1[c], bf,
                                                               acc[1][nt], 0, 0, 0);
        }
      }
      __builtin_amdgcn_s_setprio(0);
      if (t < 8) {
#pragma unroll
        for (int c = 0; c < 4; ++c) { a0[c] = a0n[c]; a1[c] = a1n[c]; }
      }
    }
    __syncthreads();  // conv2 reads of h1g done -> reuse as h2t

    // h2 (ReLU+bias, bf16) -> LDS cg-major [cg][px][8]
    short* h2t = h1g;
#pragma unroll
    for (int nt = 0; nt < 2; ++nt) {
      int px = (wv << 6) + (nt << 5) + l31;
#pragma unroll
      for (int cb = 0; cb < 2; ++cb) {
#pragma unroll
        for (int q = 0; q < 4; ++q) {
          int ch0 = cb * 32 + 8 * q + 4 * lh;
          f32x4 bv = *reinterpret_cast<const f32x4*>(&b2v[ch0]);
          short4v o;
#pragma unroll
          for (int j = 0; j < 4; ++j) {
            float v = acc[cb][nt][4 * q + j] + bv[j];
            o[j] = f2bf(v > 0.f ? v : 0.f);
          }
          int cg = cb * 4 + q;
          *reinterpret_cast<short4v*>(&h2t[(cg * 256 + px) * 8 + 4 * lh]) = o;
        }
      }
    }
    // depthwise conv3 — wave-local px, no barrier needed
    short8 af3[4];
#pragma unroll
    for (int c = 0; c < 4; ++c)
      af3[c] = *reinterpret_cast<const short8*>(
          (const char*)w3b + c * 1024 + lane * 16);
#pragma unroll
    for (int nt = 0; nt < 2; ++nt) {
      int pxb = (wv << 6) + (nt << 5);
      f32x16 d;
#pragma unroll
      for (int r = 0; r < 16; ++r) d[r] = 0.f;
      __builtin_amdgcn_s_setprio(1);
#pragma unroll
      for (int c = 0; c < 4; ++c) {
        short8 bf = *reinterpret_cast<const short8*>(
            (const char*)h2t + ((2 * c + lh) * 256 + pxb + l31) * 16);
        d = __builtin_amdgcn_mfma_f32_32x32x16_bf16(af3[c], bf, d, 0, 0, 0);
      }
      __builtin_amdgcn_s_setprio(0);
      int px = pxb + l31;
      int gpx = ((y0 + (px >> 4)) << 7) + x0 + (px & 15);
      if (lh == 0) {
#pragma unroll
        for (int r = 0; r < 4; ++r)
          D_ws[((size_t)(r * BC + bl) << 14) + gpx] = d[r];
        D_ws[((size_t)(8 * BC + bl) << 14) + gpx] = d[4];
      } else {
#pragma unroll
        for (int r = 0; r < 4; ++r)
          D_ws[((size_t)((4 + r) * BC + bl) << 14) + gpx] = d[r];
      }
    }
  }
}

// ---------------- conv3 shift-sum + u update (memory-bound) -------------
__global__ __launch_bounds__(256) void mlstep_b(
    const float* __restrict__ D_ws, const float* __restrict__ b3,
    const float* __restrict__ uprev, float* __restrict__ uout,
    int b0, int BC) {
  int idx = blockIdx.x * 256 + threadIdx.x;
  int bl = idx >> 14;
  int rem = idx & (SPAT - 1);
  int y = rem >> 7, x = rem & NMASK;
  float acc = b3[0];
#pragma unroll
  for (int t = 0; t < 9; ++t) {
    int yy = (y + t / 3 - 1) & NMASK;
    int xx = (x + t % 3 - 1) & NMASK;
    acc += D_ws[((size_t)(t * BC + bl) << 14) + (yy << 7) + xx];
  }
  size_t g = ((size_t)(b0 + bl) << 14) + rem;
  uout[g] = uprev[g] + acc;
}

// ---------------- routing scores ----------------------------------------
__global__ void scores_kernel(float* __restrict__ s) {
  int i = blockIdx.x * 256 + threadIdx.x;
  if (i < 8 * BS * 2) {
    int it = i >> 6;
    int k = i & 1;
    bool ml = (it & 3) == 3;
    s[i] = ml ? (float)k : (float)(1 - k);
  }
}

extern "C" void kernel_launch(void* const* d_in, const int* in_sizes, int n_in,
                              void* d_out, int out_size, void* d_ws,
                              size_t ws_size, hipStream_t stream) {
  (void)in_sizes; (void)n_in; (void)out_size;
  const float* f  = (const float*)d_in[0];
  const float* u0 = (const float*)d_in[1];
  const float* w1 = (const float*)d_in[2];
  const float* b1 = (const float*)d_in[3];
  const float* w2 = (const float*)d_in[4];
  const float* b2 = (const float*)d_in[5];
  const float* w3 = (const float*)d_in[6];
  const float* b3 = (const float*)d_in[7];

  float* preds  = (float*)d_out;                  // [8][32][128][128]
  float* scores = preds + (size_t)8 * BS * SPAT;  // [8][32][2]

  short* w2b = (short*)d_ws;                       // 73728 B
  short* w1a = w2b + 36864;                        // 2048 B
  short* w3b = w1a + 1024;                         // 4096 B
  float* res_ws = (float*)(w3b + 2048);            // 2 MB
  float* D_ws = res_ws + (size_t)BS * SPAT;        // 9*BC*64KB
  size_t fixed = (size_t)(36864 + 1024 + 2048) * 2 + (size_t)BS * SPAT * 4;
  size_t avail = ws_size > fixed ? ws_size - fixed : 0;
  int BC = 32;
  while (BC > 1 && (size_t)BC * ((size_t)9 * SPAT * 4) > avail) BC >>= 1;

  prep_kernel<<<156, 256, 0, stream>>>(w2, w1, w3, w2b, w1a, w3b);

  for (int p = 0; p < 2; ++p) {
    int it = 4 * p;
    const float* up = (p == 0) ? u0 : preds + (size_t)3 * BS * SPAT;
    float* u1o = preds + (size_t)(it + 0) * BS * SPAT;
    float* u2o = preds + (size_t)(it + 1) * BS * SPAT;
    float* u3o = preds + (size_t)(it + 2) * BS * SPAT;
    float* umo = preds + (size_t)(it + 3) * BS * SPAT;
    jac3_kernel<<<BS * 64, 256, 0, stream>>>(up, f, u1o, u2o, u3o, res_ws);
    for (int b0 = 0; b0 < BS; b0 += BC) {
      mlstep_a<<<BC * 64, 256, 0, stream>>>(res_ws, w1a, b1, w2b, b2, w3b,
                                            D_ws, b0, BC);
      mlstep_b<<<BC * SPAT / 256, 256, 0, stream>>>(D_ws, b3, u3o, umo, b0, BC);
    }
  }
  scores_kernel<<<2, 256, 0, stream>>>(scores);
}